// Round 1
// baseline (1409.621 us; speedup 1.0000x reference)
//
#include <hip/hip_runtime.h>
#include <hip/hip_bf16.h>

// GPT-2-ish forward: L=4, B=2, T=1024, C=1024, H=16, D=64, V=50257.
// Output: last-position logits [B,1,V] fp32.
// Strategy: bf16 MFMA GEMMs (fp32 accum), fp32 residual path, flash attention.

#define TT 1024
#define CC 1024
#define NHEAD 16
#define DHEAD 64
#define NBATCH 2
#define VOCAB 50257

typedef __attribute__((ext_vector_type(8))) short bf16x8;
typedef __attribute__((ext_vector_type(4))) float f32x4;

__device__ __forceinline__ unsigned short f2bf(float f) {
  union { float f; unsigned u; } v; v.f = f;
  unsigned r = v.u + 0x7fffu + ((v.u >> 16) & 1u);   // RNE
  return (unsigned short)(r >> 16);
}

__device__ __forceinline__ f32x4 mfma_bf16(bf16x8 a, bf16x8 b, f32x4 c) {
  return __builtin_amdgcn_mfma_f32_16x16x32_bf16(a, b, c, 0, 0, 0);
}

// ---------------- embedding: x = wte[idx] + wpe[t] ----------------
__global__ __launch_bounds__(256) void embed_k(const int* __restrict__ idx,
    const float* __restrict__ wte, const float* __restrict__ wpe,
    float* __restrict__ x)
{
  int row = blockIdx.x;              // 0..2047
  int t = row & (TT - 1);
  int tok = idx[row];
  const float4* a = (const float4*)(wte + (size_t)tok * CC);
  const float4* p = (const float4*)(wpe + (size_t)t * CC);
  float4* o = (float4*)(x + (size_t)row * CC);
  int i = threadIdx.x;               // 256 float4 per row
  float4 va = a[i], vp = p[i];
  o[i] = make_float4(va.x + vp.x, va.y + vp.y, va.z + vp.z, va.w + vp.w);
}

// ---------------- layernorm (fp32 in -> bf16 out), one wave per row ----------------
__device__ __forceinline__ unsigned pk2(float lo, float hi) {
  return (unsigned)f2bf(lo) | ((unsigned)f2bf(hi) << 16);
}

__global__ __launch_bounds__(256) void ln_k(const float* __restrict__ x,
    const float* __restrict__ w, const float* __restrict__ b,
    unsigned short* __restrict__ out)
{
  int row = blockIdx.x * 4 + (threadIdx.x >> 6);
  int lane = threadIdx.x & 63;
  const float* xr = x + (size_t)row * CC + lane * 16;
  float4 v[4];
  float s = 0.f, ss = 0.f;
#pragma unroll
  for (int i = 0; i < 4; ++i) {
    v[i] = *(const float4*)(xr + i * 4);
    s  += v[i].x + v[i].y + v[i].z + v[i].w;
    ss += v[i].x*v[i].x + v[i].y*v[i].y + v[i].z*v[i].z + v[i].w*v[i].w;
  }
#pragma unroll
  for (int off = 1; off < 64; off <<= 1) {
    s  += __shfl_xor(s, off, 64);
    ss += __shfl_xor(ss, off, 64);
  }
  float mu = s * (1.f / CC);
  float var = ss * (1.f / CC) - mu * mu;
  float rstd = rsqrtf(var + 1e-5f);
  const float* wr = w + lane * 16;
  const float* br = b + lane * 16;
  unsigned q[8];
#pragma unroll
  for (int i = 0; i < 4; ++i) {
    float4 wv = *(const float4*)(wr + i * 4);
    float4 bv = *(const float4*)(br + i * 4);
    float o0 = (v[i].x - mu) * rstd * wv.x + bv.x;
    float o1 = (v[i].y - mu) * rstd * wv.y + bv.y;
    float o2 = (v[i].z - mu) * rstd * wv.z + bv.z;
    float o3 = (v[i].w - mu) * rstd * wv.w + bv.w;
    q[i*2+0] = pk2(o0, o1);
    q[i*2+1] = pk2(o2, o3);
  }
  uint4* op = (uint4*)(out + (size_t)row * CC + lane * 16);
  op[0] = make_uint4(q[0], q[1], q[2], q[3]);
  op[1] = make_uint4(q[4], q[5], q[6], q[7]);
}

// ---------------- final LN on the two last-position rows only (fp32 out) ----------------
__global__ void lnf_k(const float* __restrict__ x,
    const float* __restrict__ w, const float* __restrict__ b,
    float* __restrict__ xf)
{
  int row = blockIdx.x;   // 0..1 (batch)
  int lane = threadIdx.x; // 64
  const float* xr = x + ((size_t)(row * TT + (TT - 1))) * CC + lane * 16;
  float4 v[4];
  float s = 0.f, ss = 0.f;
#pragma unroll
  for (int i = 0; i < 4; ++i) {
    v[i] = *(const float4*)(xr + i * 4);
    s  += v[i].x + v[i].y + v[i].z + v[i].w;
    ss += v[i].x*v[i].x + v[i].y*v[i].y + v[i].z*v[i].z + v[i].w*v[i].w;
  }
#pragma unroll
  for (int off = 1; off < 64; off <<= 1) {
    s  += __shfl_xor(s, off, 64);
    ss += __shfl_xor(ss, off, 64);
  }
  float mu = s * (1.f / CC);
  float var = ss * (1.f / CC) - mu * mu;
  float rstd = rsqrtf(var + 1e-5f);
  float* op = xf + (size_t)row * CC + lane * 16;
  const float* wr = w + lane * 16;
  const float* br = b + lane * 16;
#pragma unroll
  for (int i = 0; i < 4; ++i) {
    float4 wv = *(const float4*)(wr + i * 4);
    float4 bv = *(const float4*)(br + i * 4);
    float4 o;
    o.x = (v[i].x - mu) * rstd * wv.x + bv.x;
    o.y = (v[i].y - mu) * rstd * wv.y + bv.y;
    o.z = (v[i].z - mu) * rstd * wv.z + bv.z;
    o.w = (v[i].w - mu) * rstd * wv.w + bv.w;
    *(float4*)(op + i * 4) = o;
  }
}

// ---------------- GEMM: out = A(bf16)[M,K] @ W(f32->bf16)[K,N] + bias ----------------
// 128x128 tile, 4 waves (2x2), each wave 64x64 via 4x4 mfma_f32_16x16x32_bf16.
#define MODE_QKV 0
#define MODE_RES 1
#define MODE_FC  2

template<int MODE>
__global__ __launch_bounds__(256) void gemm_k(
    const unsigned short* __restrict__ A,
    const float* __restrict__ W,
    const float* __restrict__ bias,
    float* __restrict__ resid,
    unsigned short* __restrict__ obf,
    unsigned short* __restrict__ q_o,
    unsigned short* __restrict__ k_o,
    unsigned short* __restrict__ v_o,
    int M, int N, int K)
{
  __shared__ alignas(16) unsigned short Asm[128][40];  // [m][k], pad->80B rows
  __shared__ alignas(16) unsigned short Bsm[128][40];  // [n][k] (W transposed)
  const int tid  = threadIdx.x;
  const int wave = tid >> 6, lane = tid & 63;
  const int lg = lane >> 4, ll = lane & 15;
  const int nTM = M >> 7;
  const int m0 = (blockIdx.x % nTM) << 7;
  const int n0 = (blockIdx.x / nTM) << 7;
  const int wm = (wave >> 1) << 6, wn = (wave & 1) << 6;
  f32x4 acc[4][4] = {};

  const int arow = tid >> 2, acq = tid & 3;   // A staging
  const int bn = tid & 127, bkh = tid >> 7;   // W staging

  for (int k0 = 0; k0 < K; k0 += 32) {
    // stage A tile 128x32 (bf16, vectorized)
#pragma unroll
    for (int p = 0; p < 2; ++p) {
      int r = arow + (p << 6);
      bf16x8 av = *(const bf16x8*)(A + (size_t)(m0 + r) * K + k0 + (acq << 3));
      *(bf16x8*)&Asm[r][acq << 3] = av;
    }
    // stage W tile 32x128 transposed -> Bsm[n][k], fp32->bf16 in-register
    {
      const float* wp = W + (size_t)(k0 + bkh * 16) * N + n0 + bn;
      bf16x8 w0, w1;
#pragma unroll
      for (int kk = 0; kk < 8; ++kk) w0[kk] = (short)f2bf(wp[(size_t)kk * N]);
#pragma unroll
      for (int kk = 0; kk < 8; ++kk) w1[kk] = (short)f2bf(wp[(size_t)(kk + 8) * N]);
      *(bf16x8*)&Bsm[bn][bkh * 16]     = w0;
      *(bf16x8*)&Bsm[bn][bkh * 16 + 8] = w1;
    }
    __syncthreads();
    bf16x8 af[4], bfr[4];
#pragma unroll
    for (int i = 0; i < 4; ++i)
      af[i] = *(const bf16x8*)&Asm[wm + i * 16 + ll][lg << 3];
#pragma unroll
    for (int j = 0; j < 4; ++j)
      bfr[j] = *(const bf16x8*)&Bsm[wn + j * 16 + ll][lg << 3];
#pragma unroll
    for (int i = 0; i < 4; ++i)
#pragma unroll
      for (int j = 0; j < 4; ++j)
        acc[i][j] = mfma_bf16(af[i], bfr[j], acc[i][j]);
    __syncthreads();
  }

  // epilogue: D[row=(lg<<2)+r (per 16-block), col=ll]
#pragma unroll
  for (int j = 0; j < 4; ++j) {
    int gc = n0 + wn + j * 16 + ll;
    float bv = bias[gc];
#pragma unroll
    for (int i = 0; i < 4; ++i) {
      int gr0 = m0 + wm + i * 16 + (lg << 2);
#pragma unroll
      for (int r = 0; r < 4; ++r) {
        int grow = gr0 + r;
        float val = acc[i][j][r] + bv;
        if (MODE == MODE_QKV) {
          int which = gc >> 10;
          int head = (gc >> 6) & 15;
          int d = gc & 63;
          int bb = grow >> 10, t = grow & (TT - 1);
          unsigned short* dst = (which == 0) ? q_o : (which == 1) ? k_o : v_o;
          dst[(((size_t)((bb << 4) + head)) << 16) + ((size_t)t << 6) + d] = f2bf(val);
        } else if (MODE == MODE_FC) {
          val = (val >= 0.f) ? val : 0.01f * val;
          obf[(size_t)grow * N + gc] = f2bf(val);
        } else { // MODE_RES: x += proj(...)
          resid[(size_t)grow * N + gc] += val;
        }
      }
    }
  }
}

// ---------------- flash attention (causal), 64 q-rows/block, 4 waves ----------------
__global__ __launch_bounds__(256) void attn_k(
    const unsigned short* __restrict__ Qb,
    const unsigned short* __restrict__ Kb,
    const unsigned short* __restrict__ Vb,
    unsigned short* __restrict__ ybuf)
{
  __shared__ alignas(16) unsigned short Ksm[64][72];   // [key][d] padded
  __shared__ alignas(16) unsigned short Vtsm[64][64];  // [d][key] 16B-unit XOR swizzled
  __shared__ alignas(16) unsigned short Psm[4][16][72];
  const int tid = threadIdx.x;
  const int wave = tid >> 6, lane = tid & 63;
  const int lg = lane >> 4, ll = lane & 15;
  const int qt = blockIdx.x & 15, bh = blockIdx.x >> 4;
  const int b = bh >> 4, h = bh & 15;
  const size_t base = (size_t)bh << 16;   // bh * T * D
  const int q0 = qt << 6;

  // Q fragments (A-layout): row = ll, k = lg*8+e (+32)
  const int qrow = q0 + wave * 16 + ll;
  bf16x8 aq0 = *(const bf16x8*)(Qb + base + ((size_t)qrow << 6) + (lg << 3));
  bf16x8 aq1 = *(const bf16x8*)(Qb + base + ((size_t)qrow << 6) + 32 + (lg << 3));

  f32x4 accy[4] = {};
  float m_run[4], l_run[4];
#pragma unroll
  for (int r = 0; r < 4; ++r) { m_run[r] = -1e30f; l_run[r] = 0.f; }

  const int sk_row = tid >> 3, sk_cq = tid & 7;
  const int sv_d = tid & 63, sv_kq = tid >> 6;
  const int qg0 = q0 + wave * 16 + (lg << 2);

  for (int kb = 0; kb <= qt; ++kb) {
    const int kbase = kb << 6;
    // stage K [64 keys][64 d]
#pragma unroll
    for (int p = 0; p < 2; ++p) {
      int r = sk_row + (p << 5);
      bf16x8 kv = *(const bf16x8*)(Kb + base + ((size_t)(kbase + r) << 6) + (sk_cq << 3));
      *(bf16x8*)&Ksm[r][sk_cq << 3] = kv;
    }
    // stage V transposed: Vtsm[d][key], unit-swizzled
#pragma unroll
    for (int p = 0; p < 2; ++p) {
      int kq8 = sv_kq + (p << 2);   // key octet 0..7
      bf16x8 wv;
#pragma unroll
      for (int e = 0; e < 8; ++e)
        wv[e] = (short)Vb[base + ((size_t)(kbase + (kq8 << 3) + e) << 6) + sv_d];
      int u = kq8 ^ (sv_d & 7);
      *(bf16x8*)&Vtsm[sv_d][u << 3] = wv;
    }
    __syncthreads();

    // S = Q K^T * scale, causal mask
    float p_[4][4];
    float rmax[4] = {-1e30f, -1e30f, -1e30f, -1e30f};
#pragma unroll
    for (int kk = 0; kk < 4; ++kk) {
      f32x4 z = {};
      bf16x8 bk0 = *(const bf16x8*)&Ksm[kk * 16 + ll][lg << 3];
      bf16x8 bk1 = *(const bf16x8*)&Ksm[kk * 16 + ll][32 + (lg << 3)];
      z = mfma_bf16(aq0, bk0, z);
      z = mfma_bf16(aq1, bk1, z);
      int key = kbase + kk * 16 + ll;
#pragma unroll
      for (int r = 0; r < 4; ++r) {
        float v = z[r] * 0.125f;               // 1/sqrt(64)
        v = (key > qg0 + r) ? -1e30f : v;
        p_[kk][r] = v;
        rmax[r] = fmaxf(rmax[r], v);
      }
    }
#pragma unroll
    for (int off = 1; off < 16; off <<= 1)
#pragma unroll
      for (int r = 0; r < 4; ++r)
        rmax[r] = fmaxf(rmax[r], __shfl_xor(rmax[r], off, 64));

    float alpha[4], rsum[4];
#pragma unroll
    for (int r = 0; r < 4; ++r) {
      float mn = fmaxf(m_run[r], rmax[r]);
      alpha[r] = __expf(m_run[r] - mn);
      m_run[r] = mn;
      rsum[r] = 0.f;
    }
#pragma unroll
    for (int kk = 0; kk < 4; ++kk)
#pragma unroll
      for (int r = 0; r < 4; ++r) {
        float e = __expf(p_[kk][r] - m_run[r]);
        p_[kk][r] = e;
        rsum[r] += e;
      }
#pragma unroll
    for (int off = 1; off < 16; off <<= 1)
#pragma unroll
      for (int r = 0; r < 4; ++r)
        rsum[r] += __shfl_xor(rsum[r], off, 64);
#pragma unroll
    for (int r = 0; r < 4; ++r)
      l_run[r] = l_run[r] * alpha[r] + rsum[r];
#pragma unroll
    for (int df = 0; df < 4; ++df)
#pragma unroll
      for (int r = 0; r < 4; ++r)
        accy[df][r] *= alpha[r];

    // P (C-layout) -> LDS -> reload in A-layout (per-wave region)
#pragma unroll
    for (int kk = 0; kk < 4; ++kk)
#pragma unroll
      for (int r = 0; r < 4; ++r)
        Psm[wave][(lg << 2) + r][kk * 16 + ll] = f2bf(p_[kk][r]);
    bf16x8 pa0 = *(const bf16x8*)&Psm[wave][ll][lg << 3];
    bf16x8 pa1 = *(const bf16x8*)&Psm[wave][ll][32 + (lg << 3)];

    // Y += P @ V
#pragma unroll
    for (int df = 0; df < 4; ++df) {
      int d = df * 16 + ll;
      int u0 = lg ^ (d & 7);
      int u1 = (4 + lg) ^ (d & 7);
      bf16x8 bv0 = *(const bf16x8*)&Vtsm[d][u0 << 3];
      bf16x8 bv1 = *(const bf16x8*)&Vtsm[d][u1 << 3];
      accy[df] = mfma_bf16(pa0, bv0, accy[df]);
      accy[df] = mfma_bf16(pa1, bv1, accy[df]);
    }
    __syncthreads();
  }

  // y[b*T+q][h*64+d] = acc / l
#pragma unroll
  for (int df = 0; df < 4; ++df)
#pragma unroll
    for (int r = 0; r < 4; ++r) {
      int qr = qg0 + r;
      float y = accy[df][r] / l_run[r];
      ybuf[(((size_t)((b << 10) + qr)) << 10) + (h << 6) + df * 16 + ll] = f2bf(y);
    }
}

// ---------------- lm_head: out[b,v] = dot(xf[b], wte[v]) ----------------
__global__ __launch_bounds__(256) void head_k(const float* __restrict__ xf,
    const float* __restrict__ wte, float* __restrict__ out)
{
  int v = (blockIdx.x << 2) + (threadIdx.x >> 6);
  if (v >= VOCAB) return;
  int lane = threadIdx.x & 63;
  const float4* wr = (const float4*)(wte + (size_t)v * CC);
  const float4* x0 = (const float4*)xf;
  const float4* x1 = (const float4*)(xf + CC);
  float a0 = 0.f, a1 = 0.f;
#pragma unroll
  for (int i = 0; i < 4; ++i) {
    float4 wv = wr[lane + i * 64];
    float4 p0 = x0[lane + i * 64];
    float4 p1 = x1[lane + i * 64];
    a0 += wv.x * p0.x + wv.y * p0.y + wv.z * p0.z + wv.w * p0.w;
    a1 += wv.x * p1.x + wv.y * p1.y + wv.z * p1.z + wv.w * p1.w;
  }
#pragma unroll
  for (int off = 1; off < 64; off <<= 1) {
    a0 += __shfl_xor(a0, off, 64);
    a1 += __shfl_xor(a1, off, 64);
  }
  if (lane == 0) {
    out[v] = a0;
    out[VOCAB + v] = a1;
  }
}

// ---------------- host orchestration ----------------
extern "C" void kernel_launch(void* const* d_in, const int* in_sizes, int n_in,
                              void* d_out, int out_size, void* d_ws, size_t ws_size,
                              hipStream_t stream)
{
  const int*   idx      = (const int*)d_in[0];
  const float* wte      = (const float*)d_in[1];
  const float* wpe      = (const float*)d_in[2];
  const float* ln1_w    = (const float*)d_in[3];
  const float* ln1_b    = (const float*)d_in[4];
  const float* attn_w   = (const float*)d_in[5];
  const float* attn_b   = (const float*)d_in[6];
  const float* proj_w   = (const float*)d_in[7];
  const float* proj_b   = (const float*)d_in[8];
  const float* ln2_w    = (const float*)d_in[9];
  const float* ln2_b    = (const float*)d_in[10];
  const float* fc_w     = (const float*)d_in[11];
  const float* fc_b     = (const float*)d_in[12];
  const float* fcproj_w = (const float*)d_in[13];
  const float* fcproj_b = (const float*)d_in[14];
  const float* lnf_w    = (const float*)d_in[15];
  const float* lnf_b    = (const float*)d_in[16];
  float* out = (float*)d_out;

  // workspace layout (~44.1 MiB)
  char* ws = (char*)d_ws;
  float*          x  = (float*)ws;                              // 8 MiB  [2048,1024] f32
  unsigned short* h  = (unsigned short*)(ws + (8u  << 20));     // 4 MiB  [2048,1024] bf16
  unsigned short* qb = (unsigned short*)(ws + (12u << 20));     // 4 MiB  [B,H,T,D]
  unsigned short* kq = (unsigned short*)(ws + (16u << 20));     // 4 MiB
  unsigned short* vb = (unsigned short*)(ws + (20u << 20));     // 4 MiB
  unsigned short* yb = (unsigned short*)(ws + (24u << 20));     // 4 MiB  [2048,1024]
  unsigned short* hf = (unsigned short*)(ws + (28u << 20));     // 16 MiB [2048,4096]
  float*          xf = (float*)(ws + (44u << 20));              // 8 KiB  [2,1024]

  embed_k<<<NBATCH * TT, 256, 0, stream>>>(idx, wte, wpe, x);

  for (int l = 0; l < 4; ++l) {
    ln_k<<<512, 256, 0, stream>>>(x, ln1_w + l * CC, ln1_b + l * CC, h);
    gemm_k<MODE_QKV><<<16 * 24, 256, 0, stream>>>(h,
        attn_w + (size_t)l * CC * 3 * CC, attn_b + (size_t)l * 3 * CC,
        nullptr, nullptr, qb, kq, vb, 2048, 3072, 1024);
    attn_k<<<NBATCH * NHEAD * 16, 256, 0, stream>>>(qb, kq, vb, yb);
    gemm_k<MODE_RES><<<16 * 8, 256, 0, stream>>>(yb,
        proj_w + (size_t)l * CC * CC, proj_b + (size_t)l * CC,
        x, nullptr, nullptr, nullptr, nullptr, 2048, 1024, 1024);
    ln_k<<<512, 256, 0, stream>>>(x, ln2_w + l * CC, ln2_b + l * CC, h);
    gemm_k<MODE_FC><<<16 * 32, 256, 0, stream>>>(h,
        fc_w + (size_t)l * CC * 4 * CC, fc_b + (size_t)l * 4 * CC,
        nullptr, hf, nullptr, nullptr, nullptr, 2048, 4096, 1024);
    gemm_k<MODE_RES><<<16 * 8, 256, 0, stream>>>(hf,
        fcproj_w + (size_t)l * 4 * CC * CC, fcproj_b + (size_t)l * CC,
        x, nullptr, nullptr, nullptr, nullptr, 2048, 1024, 4096);
  }

  lnf_k<<<2, 64, 0, stream>>>(x, lnf_w, lnf_b, xf);
  head_k<<<(VOCAB + 3) / 4, 256, 0, stream>>>(xf, wte, out);
}

// Round 2
// 823.814 us; speedup vs baseline: 1.7111x; 1.7111x over previous
//
#include <hip/hip_runtime.h>
#include <hip/hip_bf16.h>

// GPT-2-ish forward: L=4, B=2, T=1024, C=1024, H=16, D=64, V=50257.
// Round 2: weights pre-transposed to bf16 [N][K]; m97-style GEMM
// (128x128 tile, BK=64, global_load_lds width 16); split-K for N=1024 GEMMs.

#define TT 1024
#define CC 1024
#define NHEAD 16
#define DHEAD 64
#define NBATCH 2
#define VOCAB 50257

typedef __attribute__((ext_vector_type(8))) short bf16x8;
typedef __attribute__((ext_vector_type(4))) float f32x4;

#define GPTR(p) (const __attribute__((address_space(1))) void*)(p)
#define LPTR(p) (__attribute__((address_space(3))) void*)(p)

__device__ __forceinline__ unsigned short f2bf(float f) {
  union { float f; unsigned u; } v; v.f = f;
  unsigned r = v.u + 0x7fffu + ((v.u >> 16) & 1u);   // RNE
  return (unsigned short)(r >> 16);
}

__device__ __forceinline__ f32x4 mfma_bf16(bf16x8 a, bf16x8 b, f32x4 c) {
  return __builtin_amdgcn_mfma_f32_16x16x32_bf16(a, b, c, 0, 0, 0);
}

// ---------------- embedding: x = wte[idx] + wpe[t] ----------------
__global__ __launch_bounds__(256) void embed_k(const int* __restrict__ idx,
    const float* __restrict__ wte, const float* __restrict__ wpe,
    float* __restrict__ x)
{
  int row = blockIdx.x;              // 0..2047
  int t = row & (TT - 1);
  int tok = idx[row];
  const float4* a = (const float4*)(wte + (size_t)tok * CC);
  const float4* p = (const float4*)(wpe + (size_t)t * CC);
  float4* o = (float4*)(x + (size_t)row * CC);
  int i = threadIdx.x;               // 256 float4 per row
  float4 va = a[i], vp = p[i];
  o[i] = make_float4(va.x + vp.x, va.y + vp.y, va.z + vp.z, va.w + vp.w);
}

// ---------------- layernorm (fp32 in -> bf16 out), one wave per row ----------------
__device__ __forceinline__ unsigned pk2(float lo, float hi) {
  return (unsigned)f2bf(lo) | ((unsigned)f2bf(hi) << 16);
}

__global__ __launch_bounds__(256) void ln_k(const float* __restrict__ x,
    const float* __restrict__ w, const float* __restrict__ b,
    unsigned short* __restrict__ out)
{
  int row = blockIdx.x * 4 + (threadIdx.x >> 6);
  int lane = threadIdx.x & 63;
  const float* xr = x + (size_t)row * CC + lane * 16;
  float4 v[4];
  float s = 0.f, ss = 0.f;
#pragma unroll
  for (int i = 0; i < 4; ++i) {
    v[i] = *(const float4*)(xr + i * 4);
    s  += v[i].x + v[i].y + v[i].z + v[i].w;
    ss += v[i].x*v[i].x + v[i].y*v[i].y + v[i].z*v[i].z + v[i].w*v[i].w;
  }
#pragma unroll
  for (int off = 1; off < 64; off <<= 1) {
    s  += __shfl_xor(s, off, 64);
    ss += __shfl_xor(ss, off, 64);
  }
  float mu = s * (1.f / CC);
  float var = ss * (1.f / CC) - mu * mu;
  float rstd = rsqrtf(var + 1e-5f);
  const float* wr = w + lane * 16;
  const float* br = b + lane * 16;
  unsigned q[8];
#pragma unroll
  for (int i = 0; i < 4; ++i) {
    float4 wv = *(const float4*)(wr + i * 4);
    float4 bv = *(const float4*)(br + i * 4);
    float o0 = (v[i].x - mu) * rstd * wv.x + bv.x;
    float o1 = (v[i].y - mu) * rstd * wv.y + bv.y;
    float o2 = (v[i].z - mu) * rstd * wv.z + bv.z;
    float o3 = (v[i].w - mu) * rstd * wv.w + bv.w;
    q[i*2+0] = pk2(o0, o1);
    q[i*2+1] = pk2(o2, o3);
  }
  uint4* op = (uint4*)(out + (size_t)row * CC + lane * 16);
  op[0] = make_uint4(q[0], q[1], q[2], q[3]);
  op[1] = make_uint4(q[4], q[5], q[6], q[7]);
}

// ---------------- final LN on the two last-position rows only (fp32 out) ----------------
__global__ void lnf_k(const float* __restrict__ x,
    const float* __restrict__ w, const float* __restrict__ b,
    float* __restrict__ xf)
{
  int row = blockIdx.x;   // 0..1 (batch)
  int lane = threadIdx.x; // 64
  const float* xr = x + ((size_t)(row * TT + (TT - 1))) * CC + lane * 16;
  float4 v[4];
  float s = 0.f, ss = 0.f;
#pragma unroll
  for (int i = 0; i < 4; ++i) {
    v[i] = *(const float4*)(xr + i * 4);
    s  += v[i].x + v[i].y + v[i].z + v[i].w;
    ss += v[i].x*v[i].x + v[i].y*v[i].y + v[i].z*v[i].z + v[i].w*v[i].w;
  }
#pragma unroll
  for (int off = 1; off < 64; off <<= 1) {
    s  += __shfl_xor(s, off, 64);
    ss += __shfl_xor(ss, off, 64);
  }
  float mu = s * (1.f / CC);
  float var = ss * (1.f / CC) - mu * mu;
  float rstd = rsqrtf(var + 1e-5f);
  float* op = xf + (size_t)row * CC + lane * 16;
  const float* wr = w + lane * 16;
  const float* br = b + lane * 16;
#pragma unroll
  for (int i = 0; i < 4; ++i) {
    float4 wv = *(const float4*)(wr + i * 4);
    float4 bv = *(const float4*)(br + i * 4);
    float4 o;
    o.x = (v[i].x - mu) * rstd * wv.x + bv.x;
    o.y = (v[i].y - mu) * rstd * wv.y + bv.y;
    o.z = (v[i].z - mu) * rstd * wv.z + bv.z;
    o.w = (v[i].w - mu) * rstd * wv.w + bv.w;
    *(float4*)(op + i * 4) = o;
  }
}

// ---------------- weight transpose+convert: W f32 [K][N] -> Wt bf16 [N][K] ----------------
__global__ __launch_bounds__(256) void wconv_k(const float* __restrict__ W,
    unsigned short* __restrict__ Wt, int K, int N)
{
  __shared__ float tile[64][65];
  const int k0 = blockIdx.x << 6;
  const int n0 = blockIdx.y << 6;
  const int t = threadIdx.x;
  {
    const int r = t >> 4, c4 = t & 15;       // 16 loader rows x 16 float4
#pragma unroll
    for (int p = 0; p < 4; ++p) {
      int kr = r + (p << 4);
      float4 v = *(const float4*)(W + (size_t)(k0 + kr) * N + n0 + (c4 << 2));
      tile[kr][(c4 << 2) + 0] = v.x;
      tile[kr][(c4 << 2) + 1] = v.y;
      tile[kr][(c4 << 2) + 2] = v.z;
      tile[kr][(c4 << 2) + 3] = v.w;
    }
  }
  __syncthreads();
  {
    const int n = t >> 2, kq = t & 3;        // each thread: 16 k's of one n-row
    bf16x8 o0, o1;
#pragma unroll
    for (int e = 0; e < 8; ++e) o0[e] = (short)f2bf(tile[(kq << 4) + e][n]);
#pragma unroll
    for (int e = 0; e < 8; ++e) o1[e] = (short)f2bf(tile[(kq << 4) + 8 + e][n]);
    unsigned short* dst = Wt + (size_t)(n0 + n) * K + k0 + (kq << 4);
    *(bf16x8*)dst = o0;
    *(bf16x8*)(dst + 8) = o1;
  }
}

// ---------------- GEMM: out = A(bf16)[M,K] @ Wt(bf16)[N,K]^T + bias ----------------
// m97 structure: 128x128 tile, BK=64, 4 waves (2x2), global_load_lds width 16.
#define MODE_QKV 0
#define MODE_RES 1
#define MODE_FC  2

template<int MODE>
__global__ __launch_bounds__(256) void gemm_k(
    const unsigned short* __restrict__ A,
    const unsigned short* __restrict__ Wt,
    const float* __restrict__ bias,
    float* __restrict__ resid,
    unsigned short* __restrict__ obf,
    unsigned short* __restrict__ q_o,
    unsigned short* __restrict__ k_o,
    unsigned short* __restrict__ v_o,
    int M, int N, int K, int kchunk)
{
  __shared__ alignas(16) unsigned short Asm[128 * 64];
  __shared__ alignas(16) unsigned short Bsm[128 * 64];
  const int tid  = threadIdx.x;
  const int wave = tid >> 6, lane = tid & 63;
  const int lg = lane >> 4, ll = lane & 15;
  const int nTM = M >> 7, nTN = N >> 7;
  int bid = blockIdx.x;
  const int mt = bid % nTM; bid /= nTM;
  const int nt = bid % nTN;
  const int s  = bid / nTN;
  const int m0 = mt << 7, n0 = nt << 7;
  const int kb = s * kchunk, ke = kb + kchunk;
  const int wm = (wave >> 1) << 6, wn = (wave & 1) << 6;
  f32x4 acc[4][4] = {};

  for (int k0 = kb; k0 < ke; k0 += 64) {
    // stage A and B tiles (128x64 bf16 each) via direct-to-LDS, 16B/lane
#pragma unroll
    for (int c = 0; c < 4; ++c) {
      const int seg = (wave << 2) + c;           // 0..15, 64 granules each
      const int g = (seg << 6) + lane;           // granule 0..1023
      const int row = g >> 3, kq = g & 7;
      const unsigned short* asrc = A  + (size_t)(m0 + row) * K + k0 + (kq << 3);
      const unsigned short* bsrc = Wt + (size_t)(n0 + row) * K + k0 + (kq << 3);
      unsigned short* adst = Asm + (size_t)(seg << 9);   // seg*64 lanes*8 elems
      unsigned short* bdst = Bsm + (size_t)(seg << 9);
      __builtin_amdgcn_global_load_lds(GPTR(asrc), LPTR(adst), 16, 0, 0);
      __builtin_amdgcn_global_load_lds(GPTR(bsrc), LPTR(bdst), 16, 0, 0);
    }
    __syncthreads();
#pragma unroll
    for (int kk = 0; kk < 2; ++kk) {
      bf16x8 af[4], bfr[4];
#pragma unroll
      for (int i = 0; i < 4; ++i)
        af[i] = *(const bf16x8*)(Asm + ((wm + i * 16 + ll) << 6) + (kk << 5) + (lg << 3));
#pragma unroll
      for (int j = 0; j < 4; ++j)
        bfr[j] = *(const bf16x8*)(Bsm + ((wn + j * 16 + ll) << 6) + (kk << 5) + (lg << 3));
#pragma unroll
      for (int i = 0; i < 4; ++i)
#pragma unroll
        for (int j = 0; j < 4; ++j)
          acc[i][j] = mfma_bf16(af[i], bfr[j], acc[i][j]);
    }
    __syncthreads();
  }

  // epilogue: D row = wm+i*16+(lg<<2)+r, col = wn+j*16+ll
#pragma unroll
  for (int j = 0; j < 4; ++j) {
    int gc = n0 + wn + j * 16 + ll;
    float bv = (kb == 0) ? bias[gc] : 0.f;
#pragma unroll
    for (int i = 0; i < 4; ++i) {
      int gr0 = m0 + wm + i * 16 + (lg << 2);
#pragma unroll
      for (int r = 0; r < 4; ++r) {
        int grow = gr0 + r;
        float val = acc[i][j][r] + bv;
        if (MODE == MODE_QKV) {
          int which = gc >> 10;
          int head = (gc >> 6) & 15;
          int d = gc & 63;
          int bb = grow >> 10, t = grow & (TT - 1);
          unsigned short* dst = (which == 0) ? q_o : (which == 1) ? k_o : v_o;
          dst[(((size_t)((bb << 4) + head)) << 16) + ((size_t)t << 6) + d] = f2bf(val);
        } else if (MODE == MODE_FC) {
          val = (val >= 0.f) ? val : 0.01f * val;
          obf[(size_t)grow * N + gc] = f2bf(val);
        } else { // MODE_RES: x += (split-K partial)
          atomicAdd(&resid[(size_t)grow * N + gc], val);
        }
      }
    }
  }
}

// ---------------- flash attention (causal), 64 q-rows/block, 4 waves ----------------
__global__ __launch_bounds__(256) void attn_k(
    const unsigned short* __restrict__ Qb,
    const unsigned short* __restrict__ Kb,
    const unsigned short* __restrict__ Vb,
    unsigned short* __restrict__ ybuf)
{
  __shared__ alignas(16) unsigned short Ksm[64][72];   // [key][d] padded
  __shared__ alignas(16) unsigned short Vtsm[64][64];  // [d][key] 16B-unit XOR swizzled
  __shared__ alignas(16) unsigned short Psm[4][16][72];
  const int tid = threadIdx.x;
  const int wave = tid >> 6, lane = tid & 63;
  const int lg = lane >> 4, ll = lane & 15;
  const int qt = blockIdx.x & 15, bh = blockIdx.x >> 4;
  const int b = bh >> 4, h = bh & 15;
  const size_t base = (size_t)bh << 16;   // bh * T * D
  const int q0 = qt << 6;

  const int qrow = q0 + wave * 16 + ll;
  bf16x8 aq0 = *(const bf16x8*)(Qb + base + ((size_t)qrow << 6) + (lg << 3));
  bf16x8 aq1 = *(const bf16x8*)(Qb + base + ((size_t)qrow << 6) + 32 + (lg << 3));

  f32x4 accy[4] = {};
  float m_run[4], l_run[4];
#pragma unroll
  for (int r = 0; r < 4; ++r) { m_run[r] = -1e30f; l_run[r] = 0.f; }

  const int sk_row = tid >> 3, sk_cq = tid & 7;
  const int sv_d = tid & 63, sv_kq = tid >> 6;
  const int qg0 = q0 + wave * 16 + (lg << 2);

  for (int kb = 0; kb <= qt; ++kb) {
    const int kbase = kb << 6;
#pragma unroll
    for (int p = 0; p < 2; ++p) {
      int r = sk_row + (p << 5);
      bf16x8 kv = *(const bf16x8*)(Kb + base + ((size_t)(kbase + r) << 6) + (sk_cq << 3));
      *(bf16x8*)&Ksm[r][sk_cq << 3] = kv;
    }
#pragma unroll
    for (int p = 0; p < 2; ++p) {
      int kq8 = sv_kq + (p << 2);
      bf16x8 wv;
#pragma unroll
      for (int e = 0; e < 8; ++e)
        wv[e] = (short)Vb[base + ((size_t)(kbase + (kq8 << 3) + e) << 6) + sv_d];
      int u = kq8 ^ (sv_d & 7);
      *(bf16x8*)&Vtsm[sv_d][u << 3] = wv;
    }
    __syncthreads();

    float p_[4][4];
    float rmax[4] = {-1e30f, -1e30f, -1e30f, -1e30f};
#pragma unroll
    for (int kk = 0; kk < 4; ++kk) {
      f32x4 z = {};
      bf16x8 bk0 = *(const bf16x8*)&Ksm[kk * 16 + ll][lg << 3];
      bf16x8 bk1 = *(const bf16x8*)&Ksm[kk * 16 + ll][32 + (lg << 3)];
      z = mfma_bf16(aq0, bk0, z);
      z = mfma_bf16(aq1, bk1, z);
      int key = kbase + kk * 16 + ll;
#pragma unroll
      for (int r = 0; r < 4; ++r) {
        float v = z[r] * 0.125f;
        v = (key > qg0 + r) ? -1e30f : v;
        p_[kk][r] = v;
        rmax[r] = fmaxf(rmax[r], v);
      }
    }
#pragma unroll
    for (int off = 1; off < 16; off <<= 1)
#pragma unroll
      for (int r = 0; r < 4; ++r)
        rmax[r] = fmaxf(rmax[r], __shfl_xor(rmax[r], off, 64));

    float alpha[4], rsum[4];
#pragma unroll
    for (int r = 0; r < 4; ++r) {
      float mn = fmaxf(m_run[r], rmax[r]);
      alpha[r] = __expf(m_run[r] - mn);
      m_run[r] = mn;
      rsum[r] = 0.f;
    }
#pragma unroll
    for (int kk = 0; kk < 4; ++kk)
#pragma unroll
      for (int r = 0; r < 4; ++r) {
        float e = __expf(p_[kk][r] - m_run[r]);
        p_[kk][r] = e;
        rsum[r] += e;
      }
#pragma unroll
    for (int off = 1; off < 16; off <<= 1)
#pragma unroll
      for (int r = 0; r < 4; ++r)
        rsum[r] += __shfl_xor(rsum[r], off, 64);
#pragma unroll
    for (int r = 0; r < 4; ++r)
      l_run[r] = l_run[r] * alpha[r] + rsum[r];
#pragma unroll
    for (int df = 0; df < 4; ++df)
#pragma unroll
      for (int r = 0; r < 4; ++r)
        accy[df][r] *= alpha[r];

#pragma unroll
    for (int kk = 0; kk < 4; ++kk)
#pragma unroll
      for (int r = 0; r < 4; ++r)
        Psm[wave][(lg << 2) + r][kk * 16 + ll] = f2bf(p_[kk][r]);
    bf16x8 pa0 = *(const bf16x8*)&Psm[wave][ll][lg << 3];
    bf16x8 pa1 = *(const bf16x8*)&Psm[wave][ll][32 + (lg << 3)];

#pragma unroll
    for (int df = 0; df < 4; ++df) {
      int d = df * 16 + ll;
      int u0 = lg ^ (d & 7);
      int u1 = (4 + lg) ^ (d & 7);
      bf16x8 bv0 = *(const bf16x8*)&Vtsm[d][u0 << 3];
      bf16x8 bv1 = *(const bf16x8*)&Vtsm[d][u1 << 3];
      accy[df] = mfma_bf16(pa0, bv0, accy[df]);
      accy[df] = mfma_bf16(pa1, bv1, accy[df]);
    }
    __syncthreads();
  }

#pragma unroll
  for (int df = 0; df < 4; ++df)
#pragma unroll
    for (int r = 0; r < 4; ++r) {
      int qr = qg0 + r;
      float y = accy[df][r] / l_run[r];
      ybuf[(((size_t)((b << 10) + qr)) << 10) + (h << 6) + df * 16 + ll] = f2bf(y);
    }
}

// ---------------- lm_head: out[b,v] = dot(xf[b], wte[v]) ----------------
__global__ __launch_bounds__(256) void head_k(const float* __restrict__ xf,
    const float* __restrict__ wte, float* __restrict__ out)
{
  int v = (blockIdx.x << 2) + (threadIdx.x >> 6);
  if (v >= VOCAB) return;
  int lane = threadIdx.x & 63;
  const float4* wr = (const float4*)(wte + (size_t)v * CC);
  const float4* x0 = (const float4*)xf;
  const float4* x1 = (const float4*)(xf + CC);
  float a0 = 0.f, a1 = 0.f;
#pragma unroll
  for (int i = 0; i < 4; ++i) {
    float4 wv = wr[lane + i * 64];
    float4 p0 = x0[lane + i * 64];
    float4 p1 = x1[lane + i * 64];
    a0 += wv.x * p0.x + wv.y * p0.y + wv.z * p0.z + wv.w * p0.w;
    a1 += wv.x * p1.x + wv.y * p1.y + wv.z * p1.z + wv.w * p1.w;
  }
#pragma unroll
  for (int off = 1; off < 64; off <<= 1) {
    a0 += __shfl_xor(a0, off, 64);
    a1 += __shfl_xor(a1, off, 64);
  }
  if (lane == 0) {
    out[v] = a0;
    out[VOCAB + v] = a1;
  }
}

// ---------------- host orchestration ----------------
extern "C" void kernel_launch(void* const* d_in, const int* in_sizes, int n_in,
                              void* d_out, int out_size, void* d_ws, size_t ws_size,
                              hipStream_t stream)
{
  const int*   idx      = (const int*)d_in[0];
  const float* wte      = (const float*)d_in[1];
  const float* wpe      = (const float*)d_in[2];
  const float* ln1_w    = (const float*)d_in[3];
  const float* ln1_b    = (const float*)d_in[4];
  const float* attn_w   = (const float*)d_in[5];
  const float* attn_b   = (const float*)d_in[6];
  const float* proj_w   = (const float*)d_in[7];
  const float* proj_b   = (const float*)d_in[8];
  const float* ln2_w    = (const float*)d_in[9];
  const float* ln2_b    = (const float*)d_in[10];
  const float* fc_w     = (const float*)d_in[11];
  const float* fc_b     = (const float*)d_in[12];
  const float* fcproj_w = (const float*)d_in[13];
  const float* fcproj_b = (const float*)d_in[14];
  const float* lnf_w    = (const float*)d_in[15];
  const float* lnf_b    = (const float*)d_in[16];
  float* out = (float*)d_out;

  // workspace layout (~69 MiB)
  char* ws = (char*)d_ws;
  float*          x   = (float*)ws;                              // 8 MiB
  unsigned short* h   = (unsigned short*)(ws + (8u  << 20));     // 4 MiB
  unsigned short* qb  = (unsigned short*)(ws + (12u << 20));     // 4 MiB
  unsigned short* kb_ = (unsigned short*)(ws + (16u << 20));     // 4 MiB
  unsigned short* vb  = (unsigned short*)(ws + (20u << 20));     // 4 MiB
  unsigned short* yb  = (unsigned short*)(ws + (24u << 20));     // 4 MiB
  unsigned short* hf  = (unsigned short*)(ws + (28u << 20));     // 16 MiB
  float*          xf  = (float*)(ws + (44u << 20));              // 8 KiB
  unsigned short* wt_attn   = (unsigned short*)(ws + (45u << 20)); // 6 MiB
  unsigned short* wt_proj   = (unsigned short*)(ws + (51u << 20)); // 2 MiB
  unsigned short* wt_fc     = (unsigned short*)(ws + (53u << 20)); // 8 MiB
  unsigned short* wt_fcproj = (unsigned short*)(ws + (61u << 20)); // 8 MiB

  embed_k<<<NBATCH * TT, 256, 0, stream>>>(idx, wte, wpe, x);

  for (int l = 0; l < 4; ++l) {
    ln_k<<<512, 256, 0, stream>>>(x, ln1_w + l * CC, ln1_b + l * CC, h);
    wconv_k<<<dim3(16, 48), 256, 0, stream>>>(attn_w + (size_t)l * CC * 3 * CC, wt_attn, 1024, 3072);
    gemm_k<MODE_QKV><<<16 * 24, 256, 0, stream>>>(h, wt_attn,
        attn_b + (size_t)l * 3 * CC, nullptr, nullptr, qb, kb_, vb,
        2048, 3072, 1024, 1024);
    attn_k<<<NBATCH * NHEAD * 16, 256, 0, stream>>>(qb, kb_, vb, yb);
    wconv_k<<<dim3(16, 16), 256, 0, stream>>>(proj_w + (size_t)l * CC * CC, wt_proj, 1024, 1024);
    gemm_k<MODE_RES><<<16 * 8 * 2, 256, 0, stream>>>(yb, wt_proj,
        proj_b + (size_t)l * CC, x, nullptr, nullptr, nullptr, nullptr,
        2048, 1024, 1024, 512);
    ln_k<<<512, 256, 0, stream>>>(x, ln2_w + l * CC, ln2_b + l * CC, h);
    wconv_k<<<dim3(16, 64), 256, 0, stream>>>(fc_w + (size_t)l * CC * 4 * CC, wt_fc, 1024, 4096);
    gemm_k<MODE_FC><<<16 * 32, 256, 0, stream>>>(h, wt_fc,
        fc_b + (size_t)l * 4 * CC, nullptr, hf, nullptr, nullptr, nullptr,
        2048, 4096, 1024, 1024);
    wconv_k<<<dim3(64, 16), 256, 0, stream>>>(fcproj_w + (size_t)l * 4 * CC * CC, wt_fcproj, 4096, 1024);
    gemm_k<MODE_RES><<<16 * 8 * 4, 256, 0, stream>>>(hf, wt_fcproj,
        fcproj_b + (size_t)l * CC, x, nullptr, nullptr, nullptr, nullptr,
        2048, 1024, 4096, 1024);
  }

  lnf_k<<<2, 64, 0, stream>>>(x, lnf_w, lnf_b, xf);
  head_k<<<(VOCAB + 3) / 4, 256, 0, stream>>>(xf, wte, out);
}

// Round 3
// 778.285 us; speedup vs baseline: 1.8112x; 1.0585x over previous
//
#include <hip/hip_runtime.h>
#include <hip/hip_bf16.h>

// GPT-2-ish forward: L=4, B=2, T=1024, C=1024, H=16, D=64, V=50257.
// Round 3: layer-4 computes only last-position outputs (KV-only qkv, 1-query
// attention, GEMV tail); split-K + partial-buffer reduce for proj/fcproj
// (no atomics); wconv batched over layers via gridDim.z.

#define TT 1024
#define CC 1024
#define NHEAD 16
#define DHEAD 64
#define NBATCH 2
#define VOCAB 50257

typedef __attribute__((ext_vector_type(8))) short bf16x8;
typedef __attribute__((ext_vector_type(4))) float f32x4;

#define GPTR(p) (const __attribute__((address_space(1))) void*)(p)
#define LPTR(p) (__attribute__((address_space(3))) void*)(p)

__device__ __forceinline__ unsigned short f2bf(float f) {
  union { float f; unsigned u; } v; v.f = f;
  unsigned r = v.u + 0x7fffu + ((v.u >> 16) & 1u);   // RNE
  return (unsigned short)(r >> 16);
}
__device__ __forceinline__ float bf2f(unsigned short u) {
  union { unsigned u; float f; } v; v.u = ((unsigned)u) << 16;
  return v.f;
}

__device__ __forceinline__ f32x4 mfma_bf16(bf16x8 a, bf16x8 b, f32x4 c) {
  return __builtin_amdgcn_mfma_f32_16x16x32_bf16(a, b, c, 0, 0, 0);
}

// ---------------- embedding ----------------
__global__ __launch_bounds__(256) void embed_k(const int* __restrict__ idx,
    const float* __restrict__ wte, const float* __restrict__ wpe,
    float* __restrict__ x)
{
  int row = blockIdx.x;
  int t = row & (TT - 1);
  int tok = idx[row];
  const float4* a = (const float4*)(wte + (size_t)tok * CC);
  const float4* p = (const float4*)(wpe + (size_t)t * CC);
  float4* o = (float4*)(x + (size_t)row * CC);
  int i = threadIdx.x;
  float4 va = a[i], vp = p[i];
  o[i] = make_float4(va.x + vp.x, va.y + vp.y, va.z + vp.z, va.w + vp.w);
}

// ---------------- layernorm fp32 -> bf16, one wave per row ----------------
__device__ __forceinline__ unsigned pk2(float lo, float hi) {
  return (unsigned)f2bf(lo) | ((unsigned)f2bf(hi) << 16);
}

__global__ __launch_bounds__(256) void ln_k(const float* __restrict__ x,
    const float* __restrict__ w, const float* __restrict__ b,
    unsigned short* __restrict__ out)
{
  int row = blockIdx.x * 4 + (threadIdx.x >> 6);
  int lane = threadIdx.x & 63;
  const float* xr = x + (size_t)row * CC + lane * 16;
  float4 v[4];
  float s = 0.f, ss = 0.f;
#pragma unroll
  for (int i = 0; i < 4; ++i) {
    v[i] = *(const float4*)(xr + i * 4);
    s  += v[i].x + v[i].y + v[i].z + v[i].w;
    ss += v[i].x*v[i].x + v[i].y*v[i].y + v[i].z*v[i].z + v[i].w*v[i].w;
  }
#pragma unroll
  for (int off = 1; off < 64; off <<= 1) {
    s  += __shfl_xor(s, off, 64);
    ss += __shfl_xor(ss, off, 64);
  }
  float mu = s * (1.f / CC);
  float var = ss * (1.f / CC) - mu * mu;
  float rstd = rsqrtf(var + 1e-5f);
  const float* wr = w + lane * 16;
  const float* br = b + lane * 16;
  unsigned q[8];
#pragma unroll
  for (int i = 0; i < 4; ++i) {
    float4 wv = *(const float4*)(wr + i * 4);
    float4 bv = *(const float4*)(br + i * 4);
    float o0 = (v[i].x - mu) * rstd * wv.x + bv.x;
    float o1 = (v[i].y - mu) * rstd * wv.y + bv.y;
    float o2 = (v[i].z - mu) * rstd * wv.z + bv.z;
    float o3 = (v[i].w - mu) * rstd * wv.w + bv.w;
    q[i*2+0] = pk2(o0, o1);
    q[i*2+1] = pk2(o2, o3);
  }
  uint4* op = (uint4*)(out + (size_t)row * CC + lane * 16);
  op[0] = make_uint4(q[0], q[1], q[2], q[3]);
  op[1] = make_uint4(q[4], q[5], q[6], q[7]);
}

// ---------------- LN of the last row per batch -> fp32 [2][C] ----------------
__global__ void lnrow_k(const float* __restrict__ x,
    const float* __restrict__ w, const float* __restrict__ b,
    float* __restrict__ outv)
{
  int row = blockIdx.x;   // batch
  int lane = threadIdx.x; // 64
  const float* xr = x + ((size_t)(row * TT + (TT - 1))) * CC + lane * 16;
  float4 v[4];
  float s = 0.f, ss = 0.f;
#pragma unroll
  for (int i = 0; i < 4; ++i) {
    v[i] = *(const float4*)(xr + i * 4);
    s  += v[i].x + v[i].y + v[i].z + v[i].w;
    ss += v[i].x*v[i].x + v[i].y*v[i].y + v[i].z*v[i].z + v[i].w*v[i].w;
  }
#pragma unroll
  for (int off = 1; off < 64; off <<= 1) {
    s  += __shfl_xor(s, off, 64);
    ss += __shfl_xor(ss, off, 64);
  }
  float mu = s * (1.f / CC);
  float var = ss * (1.f / CC) - mu * mu;
  float rstd = rsqrtf(var + 1e-5f);
  float* op = outv + (size_t)row * CC + lane * 16;
  const float* wr = w + lane * 16;
  const float* br = b + lane * 16;
#pragma unroll
  for (int i = 0; i < 4; ++i) {
    float4 wv = *(const float4*)(wr + i * 4);
    float4 bv = *(const float4*)(br + i * 4);
    float4 o;
    o.x = (v[i].x - mu) * rstd * wv.x + bv.x;
    o.y = (v[i].y - mu) * rstd * wv.y + bv.y;
    o.z = (v[i].z - mu) * rstd * wv.z + bv.z;
    o.w = (v[i].w - mu) * rstd * wv.w + bv.w;
    *(float4*)(op + i * 4) = o;
  }
}

// ---------------- weight transpose+convert, batched over layers (z) ----------------
__global__ __launch_bounds__(256) void wconv_k(const float* __restrict__ W,
    unsigned short* __restrict__ Wt, int K, int N)
{
  const size_t lo = (size_t)blockIdx.z * K * N;
  __shared__ float tile[64][65];
  const int k0 = blockIdx.x << 6;
  const int n0 = blockIdx.y << 6;
  const int t = threadIdx.x;
  {
    const int r = t >> 4, c4 = t & 15;
#pragma unroll
    for (int p = 0; p < 4; ++p) {
      int kr = r + (p << 4);
      float4 v = *(const float4*)(W + lo + (size_t)(k0 + kr) * N + n0 + (c4 << 2));
      tile[kr][(c4 << 2) + 0] = v.x;
      tile[kr][(c4 << 2) + 1] = v.y;
      tile[kr][(c4 << 2) + 2] = v.z;
      tile[kr][(c4 << 2) + 3] = v.w;
    }
  }
  __syncthreads();
  {
    const int n = t >> 2, kq = t & 3;
    bf16x8 o0, o1;
#pragma unroll
    for (int e = 0; e < 8; ++e) o0[e] = (short)f2bf(tile[(kq << 4) + e][n]);
#pragma unroll
    for (int e = 0; e < 8; ++e) o1[e] = (short)f2bf(tile[(kq << 4) + 8 + e][n]);
    unsigned short* dst = Wt + lo + (size_t)(n0 + n) * K + k0 + (kq << 4);
    *(bf16x8*)dst = o0;
    *(bf16x8*)(dst + 8) = o1;
  }
}

// ---------------- GEMM modes ----------------
#define MODE_QKV  0
#define MODE_PART 1
#define MODE_FC   2

template<int MODE>
__global__ __launch_bounds__(256) void gemm_k(
    const unsigned short* __restrict__ A,
    const unsigned short* __restrict__ Wt,
    const float* __restrict__ bias,
    float* __restrict__ pbuf,
    unsigned short* __restrict__ obf,
    unsigned short* __restrict__ q_o,
    unsigned short* __restrict__ k_o,
    unsigned short* __restrict__ v_o,
    int M, int N, int K, int kchunk, int ncol0)
{
  __shared__ alignas(16) unsigned short Asm[128 * 64];
  __shared__ alignas(16) unsigned short Bsm[128 * 64];
  const int tid  = threadIdx.x;
  const int wave = tid >> 6, lane = tid & 63;
  const int lg = lane >> 4, ll = lane & 15;
  const int nTM = M >> 7, nTN = N >> 7;
  int bid = blockIdx.x;
  const int mt = bid % nTM; bid /= nTM;
  const int nt = bid % nTN;
  const int s  = bid / nTN;
  const int m0 = mt << 7, n0 = nt << 7;
  const int kb = s * kchunk, ke = kb + kchunk;
  const int wm = (wave >> 1) << 6, wn = (wave & 1) << 6;
  f32x4 acc[4][4] = {};

  for (int k0 = kb; k0 < ke; k0 += 64) {
#pragma unroll
    for (int c = 0; c < 4; ++c) {
      const int seg = (wave << 2) + c;
      const int g = (seg << 6) + lane;
      const int row = g >> 3, kq = g & 7;
      const unsigned short* asrc = A  + (size_t)(m0 + row) * K + k0 + (kq << 3);
      const unsigned short* bsrc = Wt + (size_t)(n0 + row) * K + k0 + (kq << 3);
      unsigned short* adst = Asm + (size_t)(seg << 9);
      unsigned short* bdst = Bsm + (size_t)(seg << 9);
      __builtin_amdgcn_global_load_lds(GPTR(asrc), LPTR(adst), 16, 0, 0);
      __builtin_amdgcn_global_load_lds(GPTR(bsrc), LPTR(bdst), 16, 0, 0);
    }
    __syncthreads();
#pragma unroll
    for (int kk = 0; kk < 2; ++kk) {
      bf16x8 af[4], bfr[4];
#pragma unroll
      for (int i = 0; i < 4; ++i)
        af[i] = *(const bf16x8*)(Asm + ((wm + i * 16 + ll) << 6) + (kk << 5) + (lg << 3));
#pragma unroll
      for (int j = 0; j < 4; ++j)
        bfr[j] = *(const bf16x8*)(Bsm + ((wn + j * 16 + ll) << 6) + (kk << 5) + (lg << 3));
#pragma unroll
      for (int i = 0; i < 4; ++i)
#pragma unroll
        for (int j = 0; j < 4; ++j)
          acc[i][j] = mfma_bf16(af[i], bfr[j], acc[i][j]);
    }
    __syncthreads();
  }

#pragma unroll
  for (int j = 0; j < 4; ++j) {
    int gc = n0 + wn + j * 16 + ll;          // local col
    int gcol = ncol0 + gc;                   // global col (QKV scatter)
    float bv = (MODE == MODE_PART) ? 0.f : bias[gcol];
#pragma unroll
    for (int i = 0; i < 4; ++i) {
      int gr0 = m0 + wm + i * 16 + (lg << 2);
#pragma unroll
      for (int r = 0; r < 4; ++r) {
        int grow = gr0 + r;
        float val = acc[i][j][r] + bv;
        if (MODE == MODE_QKV) {
          int which = gcol >> 10;
          int head = (gcol >> 6) & 15;
          int d = gcol & 63;
          int bb = grow >> 10, t = grow & (TT - 1);
          unsigned short* dst = (which == 0) ? q_o : (which == 1) ? k_o : v_o;
          dst[(((size_t)((bb << 4) + head)) << 16) + ((size_t)t << 6) + d] = f2bf(val);
        } else if (MODE == MODE_FC) {
          val = (val >= 0.f) ? val : 0.01f * val;
          obf[(size_t)grow * N + gc] = f2bf(val);
        } else { // MODE_PART: fp32 partials per split
          pbuf[((size_t)s * M + grow) * N + gc] = val;
        }
      }
    }
  }
}

// ---------------- reduce: x += bias + sum_s P[s] ----------------
__global__ __launch_bounds__(256) void reduce_k(float* __restrict__ x,
    const float* __restrict__ P, const float* __restrict__ bias,
    int N4, int total4, int splits)
{
  const float4* P4 = (const float4*)P;
  const float4* b4 = (const float4*)bias;
  float4* x4 = (float4*)x;
  int stride = gridDim.x * 256;
  for (int i = blockIdx.x * 256 + threadIdx.x; i < total4; i += stride) {
    float4 s = b4[i & (N4 - 1)];
    for (int sp = 0; sp < splits; ++sp) {
      float4 p = P4[(size_t)sp * total4 + i];
      s.x += p.x; s.y += p.y; s.z += p.z; s.w += p.w;
    }
    float4 xv = x4[i];
    x4[i] = make_float4(xv.x + s.x, xv.y + s.y, xv.z + s.z, xv.w + s.w);
  }
}

// ---------------- flash attention (causal), layers 0-2 ----------------
__global__ __launch_bounds__(256) void attn_k(
    const unsigned short* __restrict__ Qb,
    const unsigned short* __restrict__ Kb,
    const unsigned short* __restrict__ Vb,
    unsigned short* __restrict__ ybuf)
{
  __shared__ alignas(16) unsigned short Ksm[64][72];
  __shared__ alignas(16) unsigned short Vtsm[64][64];
  __shared__ alignas(16) unsigned short Psm[4][16][72];
  const int tid = threadIdx.x;
  const int wave = tid >> 6, lane = tid & 63;
  const int lg = lane >> 4, ll = lane & 15;
  const int qt = blockIdx.x & 15, bh = blockIdx.x >> 4;
  const int b = bh >> 4, h = bh & 15;
  const size_t base = (size_t)bh << 16;
  const int q0 = qt << 6;

  const int qrow = q0 + wave * 16 + ll;
  bf16x8 aq0 = *(const bf16x8*)(Qb + base + ((size_t)qrow << 6) + (lg << 3));
  bf16x8 aq1 = *(const bf16x8*)(Qb + base + ((size_t)qrow << 6) + 32 + (lg << 3));

  f32x4 accy[4] = {};
  float m_run[4], l_run[4];
#pragma unroll
  for (int r = 0; r < 4; ++r) { m_run[r] = -1e30f; l_run[r] = 0.f; }

  const int sk_row = tid >> 3, sk_cq = tid & 7;
  const int sv_d = tid & 63, sv_kq = tid >> 6;
  const int qg0 = q0 + wave * 16 + (lg << 2);

  for (int kb = 0; kb <= qt; ++kb) {
    const int kbase = kb << 6;
#pragma unroll
    for (int p = 0; p < 2; ++p) {
      int r = sk_row + (p << 5);
      bf16x8 kv = *(const bf16x8*)(Kb + base + ((size_t)(kbase + r) << 6) + (sk_cq << 3));
      *(bf16x8*)&Ksm[r][sk_cq << 3] = kv;
    }
#pragma unroll
    for (int p = 0; p < 2; ++p) {
      int kq8 = sv_kq + (p << 2);
      bf16x8 wv;
#pragma unroll
      for (int e = 0; e < 8; ++e)
        wv[e] = (short)Vb[base + ((size_t)(kbase + (kq8 << 3) + e) << 6) + sv_d];
      int u = kq8 ^ (sv_d & 7);
      *(bf16x8*)&Vtsm[sv_d][u << 3] = wv;
    }
    __syncthreads();

    float p_[4][4];
    float rmax[4] = {-1e30f, -1e30f, -1e30f, -1e30f};
#pragma unroll
    for (int kk = 0; kk < 4; ++kk) {
      f32x4 z = {};
      bf16x8 bk0 = *(const bf16x8*)&Ksm[kk * 16 + ll][lg << 3];
      bf16x8 bk1 = *(const bf16x8*)&Ksm[kk * 16 + ll][32 + (lg << 3)];
      z = mfma_bf16(aq0, bk0, z);
      z = mfma_bf16(aq1, bk1, z);
      int key = kbase + kk * 16 + ll;
#pragma unroll
      for (int r = 0; r < 4; ++r) {
        float v = z[r] * 0.125f;
        v = (key > qg0 + r) ? -1e30f : v;
        p_[kk][r] = v;
        rmax[r] = fmaxf(rmax[r], v);
      }
    }
#pragma unroll
    for (int off = 1; off < 16; off <<= 1)
#pragma unroll
      for (int r = 0; r < 4; ++r)
        rmax[r] = fmaxf(rmax[r], __shfl_xor(rmax[r], off, 64));

    float alpha[4], rsum[4];
#pragma unroll
    for (int r = 0; r < 4; ++r) {
      float mn = fmaxf(m_run[r], rmax[r]);
      alpha[r] = __expf(m_run[r] - mn);
      m_run[r] = mn;
      rsum[r] = 0.f;
    }
#pragma unroll
    for (int kk = 0; kk < 4; ++kk)
#pragma unroll
      for (int r = 0; r < 4; ++r) {
        float e = __expf(p_[kk][r] - m_run[r]);
        p_[kk][r] = e;
        rsum[r] += e;
      }
#pragma unroll
    for (int off = 1; off < 16; off <<= 1)
#pragma unroll
      for (int r = 0; r < 4; ++r)
        rsum[r] += __shfl_xor(rsum[r], off, 64);
#pragma unroll
    for (int r = 0; r < 4; ++r)
      l_run[r] = l_run[r] * alpha[r] + rsum[r];
#pragma unroll
    for (int df = 0; df < 4; ++df)
#pragma unroll
      for (int r = 0; r < 4; ++r)
        accy[df][r] *= alpha[r];

#pragma unroll
    for (int kk = 0; kk < 4; ++kk)
#pragma unroll
      for (int r = 0; r < 4; ++r)
        Psm[wave][(lg << 2) + r][kk * 16 + ll] = f2bf(p_[kk][r]);
    bf16x8 pa0 = *(const bf16x8*)&Psm[wave][ll][lg << 3];
    bf16x8 pa1 = *(const bf16x8*)&Psm[wave][ll][32 + (lg << 3)];

#pragma unroll
    for (int df = 0; df < 4; ++df) {
      int d = df * 16 + ll;
      int u0 = lg ^ (d & 7);
      int u1 = (4 + lg) ^ (d & 7);
      bf16x8 bv0 = *(const bf16x8*)&Vtsm[d][u0 << 3];
      bf16x8 bv1 = *(const bf16x8*)&Vtsm[d][u1 << 3];
      accy[df] = mfma_bf16(pa0, bv0, accy[df]);
      accy[df] = mfma_bf16(pa1, bv1, accy[df]);
    }
    __syncthreads();
  }

#pragma unroll
  for (int df = 0; df < 4; ++df)
#pragma unroll
    for (int r = 0; r < 4; ++r) {
      int qr = qg0 + r;
      float y = accy[df][r] / l_run[r];
      ybuf[(((size_t)((b << 10) + qr)) << 10) + (h << 6) + df * 16 + ll] = f2bf(y);
    }
}

// ---------------- GEMV stage 1: partials over 128-k slabs ----------------
// part[(ks*2+b)*N + n] = sum_{k in slab} xv[b][k] * W[k*ldw + n]
__global__ __launch_bounds__(256) void gemv_k(const float* __restrict__ W,
    int ldw, const float* __restrict__ xv, int K,
    float* __restrict__ part, int N)
{
  __shared__ float xs[2][128];
  const int tid = threadIdx.x;
  const int n = blockIdx.x * 256 + tid;
  const int ks = blockIdx.y;
  if (tid < 128) xs[0][tid] = xv[ks * 128 + tid];
  else           xs[1][tid - 128] = xv[K + ks * 128 + (tid - 128)];
  __syncthreads();
  float a0 = 0.f, a1 = 0.f;
  const float* wp = W + (size_t)(ks * 128) * ldw + n;
#pragma unroll 4
  for (int k = 0; k < 128; ++k) {
    float w = wp[(size_t)k * ldw];
    a0 += xs[0][k] * w;
    a1 += xs[1][k] * w;
  }
  part[((size_t)ks * 2 + 0) * N + n] = a0;
  part[((size_t)ks * 2 + 1) * N + n] = a1;
}

// ---------------- GEMV merge ----------------
#define MG_PLAIN 0
#define MG_LEAKY 1
#define MG_ADDX  2
template<int MG>
__global__ __launch_bounds__(256) void gmerge_k(const float* __restrict__ part,
    const float* __restrict__ bias, float* __restrict__ outp, int N, int KT)
{
  int n = blockIdx.x * 256 + threadIdx.x;
#pragma unroll
  for (int b = 0; b < 2; ++b) {
    float s = bias[n];
    for (int ks = 0; ks < KT; ++ks)
      s += part[((size_t)ks * 2 + b) * N + n];
    if (MG == MG_PLAIN) outp[(size_t)b * N + n] = s;
    else if (MG == MG_LEAKY) outp[(size_t)b * N + n] = (s >= 0.f) ? s : 0.01f * s;
    else x_add: outp[((size_t)(b * TT + TT - 1)) * CC + n] += s;
  }
}

// ---------------- last-query attention, split over key slabs ----------------
// blockIdx.x = bh (32), blockIdx.y = ks (4); 256-key slab, 4 waves x 64 keys.
__global__ __launch_bounds__(256) void attnlast_k(
    const float* __restrict__ q_last,
    const unsigned short* __restrict__ Kb,
    const unsigned short* __restrict__ Vb,
    float* __restrict__ apart)
{
  __shared__ float qs[64];
  __shared__ float wm[4], wl[4], wacc[4][64];
  const int tid = threadIdx.x;
  const int wave = tid >> 6, lane = tid & 63;
  const int bh = blockIdx.x, ks = blockIdx.y;
  const int b = bh >> 4, h = bh & 15;
  const size_t base = (size_t)bh << 16;
  const int key = ks * 256 + wave * 64 + lane;

  if (tid < 64) qs[tid] = q_last[b * CC + h * 64 + tid];
  __syncthreads();

  // s = q . K[key]
  float s = 0.f;
  const unsigned short* kp = Kb + base + ((size_t)key << 6);
#pragma unroll
  for (int o = 0; o < 8; ++o) {
    bf16x8 kv = *(const bf16x8*)(kp + (o << 3));
#pragma unroll
    for (int e = 0; e < 8; ++e)
      s += qs[(o << 3) + e] * bf2f((unsigned short)kv[e]);
  }
  s *= 0.125f;
  float m = s;
#pragma unroll
  for (int off = 1; off < 64; off <<= 1)
    m = fmaxf(m, __shfl_xor(m, off, 64));
  float p = __expf(s - m);
  float l = p;
#pragma unroll
  for (int off = 1; off < 64; off <<= 1)
    l += __shfl_xor(l, off, 64);

  // acc[d=lane] = sum_j p_j * V[key_j][d]
  float acc = 0.f;
  const unsigned short* vp = Vb + base + ((size_t)(ks * 256 + wave * 64) << 6);
  for (int j = 0; j < 64; ++j) {
    float pj = __shfl(p, j, 64);
    acc += pj * bf2f(vp[((size_t)j << 6) + lane]);
  }
  if (lane == 0) { wm[wave] = m; wl[wave] = l; }
  wacc[wave][lane] = acc;
  __syncthreads();
  if (wave == 0) {
    float m0 = fmaxf(fmaxf(wm[0], wm[1]), fmaxf(wm[2], wm[3]));
    float lt = 0.f, at = 0.f;
#pragma unroll
    for (int sI = 0; sI < 4; ++sI) {
      float f = __expf(wm[sI] - m0);
      lt += wl[sI] * f;
      at += wacc[sI][lane] * f;
    }
    float* op = apart + ((size_t)bh * 4 + ks) * 66;
    if (lane == 0) { op[0] = m0; op[1] = lt; }
    op[2 + lane] = at;
  }
}

__global__ void attnmerge_k(const float* __restrict__ apart,
    float* __restrict__ y_last)
{
  const int bh = blockIdx.x, lane = threadIdx.x;  // 64 threads
  const int b = bh >> 4, h = bh & 15;
  const float* p0 = apart + (size_t)bh * 4 * 66;
  float m0 = fmaxf(fmaxf(p0[0], p0[66]), fmaxf(p0[132], p0[198]));
  float lt = 0.f, at = 0.f;
#pragma unroll
  for (int s = 0; s < 4; ++s) {
    const float* ps = p0 + s * 66;
    float f = __expf(ps[0] - m0);
    lt += ps[1] * f;
    at += ps[2 + lane] * f;
  }
  y_last[b * CC + h * 64 + lane] = at / lt;
}

// ---------------- lm_head ----------------
__global__ __launch_bounds__(256) void head_k(const float* __restrict__ xf,
    const float* __restrict__ wte, float* __restrict__ out)
{
  int v = (blockIdx.x << 2) + (threadIdx.x >> 6);
  if (v >= VOCAB) return;
  int lane = threadIdx.x & 63;
  const float4* wr = (const float4*)(wte + (size_t)v * CC);
  const float4* x0 = (const float4*)xf;
  const float4* x1 = (const float4*)(xf + CC);
  float a0 = 0.f, a1 = 0.f;
#pragma unroll
  for (int i = 0; i < 4; ++i) {
    float4 wv = wr[lane + i * 64];
    float4 p0 = x0[lane + i * 64];
    float4 p1 = x1[lane + i * 64];
    a0 += wv.x * p0.x + wv.y * p0.y + wv.z * p0.z + wv.w * p0.w;
    a1 += wv.x * p1.x + wv.y * p1.y + wv.z * p1.z + wv.w * p1.w;
  }
#pragma unroll
  for (int off = 1; off < 64; off <<= 1) {
    a0 += __shfl_xor(a0, off, 64);
    a1 += __shfl_xor(a1, off, 64);
  }
  if (lane == 0) {
    out[v] = a0;
    out[VOCAB + v] = a1;
  }
}

// ---------------- host orchestration ----------------
extern "C" void kernel_launch(void* const* d_in, const int* in_sizes, int n_in,
                              void* d_out, int out_size, void* d_ws, size_t ws_size,
                              hipStream_t stream)
{
  const int*   idx      = (const int*)d_in[0];
  const float* wte      = (const float*)d_in[1];
  const float* wpe      = (const float*)d_in[2];
  const float* ln1_w    = (const float*)d_in[3];
  const float* ln1_b    = (const float*)d_in[4];
  const float* attn_w   = (const float*)d_in[5];
  const float* attn_b   = (const float*)d_in[6];
  const float* proj_w   = (const float*)d_in[7];
  const float* proj_b   = (const float*)d_in[8];
  const float* ln2_w    = (const float*)d_in[9];
  const float* ln2_b    = (const float*)d_in[10];
  const float* fc_w     = (const float*)d_in[11];
  const float* fc_b     = (const float*)d_in[12];
  const float* fcproj_w = (const float*)d_in[13];
  const float* fcproj_b = (const float*)d_in[14];
  const float* lnf_w    = (const float*)d_in[15];
  const float* lnf_b    = (const float*)d_in[16];
  float* out = (float*)d_out;

  const size_t MB = 1u << 20;
  char* ws = (char*)d_ws;
  float*          x   = (float*)ws;                       // 8 MiB
  unsigned short* h   = (unsigned short*)(ws + 8*MB);     // 4 MiB
  unsigned short* qb  = (unsigned short*)(ws + 12*MB);    // 4 MiB
  unsigned short* kb_ = (unsigned short*)(ws + 16*MB);    // 4 MiB
  unsigned short* vb  = (unsigned short*)(ws + 20*MB);    // 4 MiB
  unsigned short* yb  = (unsigned short*)(ws + 24*MB);    // 4 MiB
  unsigned short* hf  = (unsigned short*)(ws + 28*MB);    // 16 MiB
  // small fp32 buffers
  char* sm = ws + 44*MB;
  float* xf     = (float*)(sm + 0);        // [2][1024]
  float* xs1    = (float*)(sm + 16*1024);  // [2][1024]
  float* xs2    = (float*)(sm + 32*1024);  // [2][1024]
  float* ylast  = (float*)(sm + 48*1024);  // [2][1024]
  float* qlast  = (float*)(sm + 64*1024);  // [2][1024]
  float* hlast  = (float*)(sm + 80*1024);  // [2][4096] (32 KiB)
  float* gpart  = (float*)(sm + 128*1024); // up to 256 KiB
  float* apart  = (float*)(sm + 512*1024); // 34 KiB
  // converted weights
  unsigned short* wt_attn   = (unsigned short*)(ws + 46*MB);  // 4 x 6 MiB
  unsigned short* wt_proj   = (unsigned short*)(ws + 70*MB);  // 3 x 2 MiB
  unsigned short* wt_fc     = (unsigned short*)(ws + 76*MB);  // 3 x 8 MiB
  unsigned short* wt_fcproj = (unsigned short*)(ws + 100*MB); // 3 x 8 MiB
  float*          Ppart     = (float*)(ws + 124*MB);          // up to 64 MiB

  embed_k<<<NBATCH * TT, 256, 0, stream>>>(idx, wte, wpe, x);

  // convert weights: attn all 4 layers; proj/fc/fcproj layers 0-2 only
  wconv_k<<<dim3(16, 48, 4), 256, 0, stream>>>(attn_w, wt_attn, 1024, 3072);
  wconv_k<<<dim3(16, 16, 3), 256, 0, stream>>>(proj_w, wt_proj, 1024, 1024);
  wconv_k<<<dim3(16, 64, 3), 256, 0, stream>>>(fc_w, wt_fc, 1024, 4096);
  wconv_k<<<dim3(64, 16, 3), 256, 0, stream>>>(fcproj_w, wt_fcproj, 4096, 1024);

  for (int l = 0; l < 3; ++l) {
    ln_k<<<512, 256, 0, stream>>>(x, ln1_w + l * CC, ln1_b + l * CC, h);
    gemm_k<MODE_QKV><<<16 * 24, 256, 0, stream>>>(h,
        wt_attn + (size_t)l * 3072 * 1024, attn_b + (size_t)l * 3 * CC,
        nullptr, nullptr, qb, kb_, vb, 2048, 3072, 1024, 1024, 0);
    attn_k<<<NBATCH * NHEAD * 16, 256, 0, stream>>>(qb, kb_, vb, yb);
    // proj: split-K 4 -> partials -> reduce into x
    gemm_k<MODE_PART><<<16 * 8 * 4, 256, 0, stream>>>(yb,
        wt_proj + (size_t)l * 1024 * 1024, nullptr,
        Ppart, nullptr, nullptr, nullptr, nullptr, 2048, 1024, 1024, 256, 0);
    reduce_k<<<512, 256, 0, stream>>>(x, Ppart, proj_b + l * CC, 256, 2048 * 256, 4);
    ln_k<<<512, 256, 0, stream>>>(x, ln2_w + l * CC, ln2_b + l * CC, h);
    gemm_k<MODE_FC><<<16 * 32, 256, 0, stream>>>(h,
        wt_fc + (size_t)l * 1024 * 4096, fc_b + (size_t)l * 4 * CC,
        nullptr, hf, nullptr, nullptr, nullptr, 2048, 4096, 1024, 1024, 0);
    // fcproj: split-K 8 -> partials -> reduce into x
    gemm_k<MODE_PART><<<16 * 8 * 8, 256, 0, stream>>>(hf,
        wt_fcproj + (size_t)l * 4096 * 1024, nullptr,
        Ppart, nullptr, nullptr, nullptr, nullptr, 2048, 1024, 4096, 512, 0);
    reduce_k<<<512, 256, 0, stream>>>(x, Ppart, fcproj_b + l * CC, 256, 2048 * 256, 8);
  }

  // ---- layer 3: K/V for all positions, everything else last-position only ----
  {
    const int l = 3;
    ln_k<<<512, 256, 0, stream>>>(x, ln1_w + l * CC, ln1_b + l * CC, h);
    // K,V only: columns [1024, 3072)
    gemm_k<MODE_QKV><<<16 * 16, 256, 0, stream>>>(h,
        wt_attn + (size_t)l * 3072 * 1024 + (size_t)1024 * 1024,
        attn_b + (size_t)l * 3 * CC,
        nullptr, nullptr, qb, kb_, vb, 2048, 2048, 1024, 1024, 1024);
    // q at last positions: ln1(x)_last @ Wq + bq
    lnrow_k<<<2, 64, 0, stream>>>(x, ln1_w + l * CC, ln1_b + l * CC, xs1);
    gemv_k<<<dim3(4, 8), 256, 0, stream>>>(attn_w + (size_t)l * CC * 3 * CC,
        3072, xs1, 1024, gpart, 1024);
    gmerge_k<MG_PLAIN><<<4, 256, 0, stream>>>(gpart, attn_b + (size_t)l * 3 * CC,
        qlast, 1024, 8);
    // attention for the 2 last queries
    attnlast_k<<<dim3(32, 4), 256, 0, stream>>>(qlast, kb_, vb, apart);
    attnmerge_k<<<32, 64, 0, stream>>>(apart, ylast);
    // proj at last positions -> x
    gemv_k<<<dim3(4, 8), 256, 0, stream>>>(proj_w + (size_t)l * CC * CC,
        1024, ylast, 1024, gpart, 1024);
    gmerge_k<MG_ADDX><<<4, 256, 0, stream>>>(gpart, proj_b + l * CC, x, 1024, 8);
    // MLP at last positions
    lnrow_k<<<2, 64, 0, stream>>>(x, ln2_w + l * CC, ln2_b + l * CC, xs2);
    gemv_k<<<dim3(16, 8), 256, 0, stream>>>(fc_w + (size_t)l * CC * 4 * CC,
        4096, xs2, 1024, gpart, 4096);
    gmerge_k<MG_LEAKY><<<16, 256, 0, stream>>>(gpart, fc_b + (size_t)l * 4 * CC,
        hlast, 4096, 8);
    gemv_k<<<dim3(4, 32), 256, 0, stream>>>(fcproj_w + (size_t)l * 4 * CC * CC,
        1024, hlast, 4096, gpart, 1024);
    gmerge_k<MG_ADDX><<<4, 256, 0, stream>>>(gpart, fcproj_b + l * CC, x, 1024, 32);
  }

  lnrow_k<<<2, 64, 0, stream>>>(x, lnf_w, lnf_b, xf);
  head_k<<<(VOCAB + 3) / 4, 256, 0, stream>>>(xf, wte, out);
}

// Round 4
// 726.152 us; speedup vs baseline: 1.9412x; 1.0718x over previous
//
#include <hip/hip_runtime.h>
#include <hip/hip_bf16.h>

// GPT-2-ish forward: L=4, B=2, T=1024, C=1024, H=16, D=64, V=50257.
// Round 4: double-buffered GEMM (prefetch-before-compute, 1 barrier/K-step),
// fcproj split-K 4, fused reduce+LN.

#define TT 1024
#define CC 1024
#define NHEAD 16
#define DHEAD 64
#define NBATCH 2
#define VOCAB 50257

typedef __attribute__((ext_vector_type(8))) short bf16x8;
typedef __attribute__((ext_vector_type(4))) float f32x4;

#define GPTR(p) (const __attribute__((address_space(1))) void*)(p)
#define LPTR(p) (__attribute__((address_space(3))) void*)(p)

__device__ __forceinline__ unsigned short f2bf(float f) {
  union { float f; unsigned u; } v; v.f = f;
  unsigned r = v.u + 0x7fffu + ((v.u >> 16) & 1u);   // RNE
  return (unsigned short)(r >> 16);
}
__device__ __forceinline__ float bf2f(unsigned short u) {
  union { unsigned u; float f; } v; v.u = ((unsigned)u) << 16;
  return v.f;
}

__device__ __forceinline__ f32x4 mfma_bf16(bf16x8 a, bf16x8 b, f32x4 c) {
  return __builtin_amdgcn_mfma_f32_16x16x32_bf16(a, b, c, 0, 0, 0);
}

// ---------------- embedding ----------------
__global__ __launch_bounds__(256) void embed_k(const int* __restrict__ idx,
    const float* __restrict__ wte, const float* __restrict__ wpe,
    float* __restrict__ x)
{
  int row = blockIdx.x;
  int t = row & (TT - 1);
  int tok = idx[row];
  const float4* a = (const float4*)(wte + (size_t)tok * CC);
  const float4* p = (const float4*)(wpe + (size_t)t * CC);
  float4* o = (float4*)(x + (size_t)row * CC);
  int i = threadIdx.x;
  float4 va = a[i], vp = p[i];
  o[i] = make_float4(va.x + vp.x, va.y + vp.y, va.z + vp.z, va.w + vp.w);
}

// ---------------- layernorm fp32 -> bf16, one wave per row ----------------
__device__ __forceinline__ unsigned pk2(float lo, float hi) {
  return (unsigned)f2bf(lo) | ((unsigned)f2bf(hi) << 16);
}

__global__ __launch_bounds__(256) void ln_k(const float* __restrict__ x,
    const float* __restrict__ w, const float* __restrict__ b,
    unsigned short* __restrict__ out)
{
  int row = blockIdx.x * 4 + (threadIdx.x >> 6);
  int lane = threadIdx.x & 63;
  const float* xr = x + (size_t)row * CC + lane * 16;
  float4 v[4];
  float s = 0.f, ss = 0.f;
#pragma unroll
  for (int i = 0; i < 4; ++i) {
    v[i] = *(const float4*)(xr + i * 4);
    s  += v[i].x + v[i].y + v[i].z + v[i].w;
    ss += v[i].x*v[i].x + v[i].y*v[i].y + v[i].z*v[i].z + v[i].w*v[i].w;
  }
#pragma unroll
  for (int off = 1; off < 64; off <<= 1) {
    s  += __shfl_xor(s, off, 64);
    ss += __shfl_xor(ss, off, 64);
  }
  float mu = s * (1.f / CC);
  float var = ss * (1.f / CC) - mu * mu;
  float rstd = rsqrtf(var + 1e-5f);
  const float* wr = w + lane * 16;
  const float* br = b + lane * 16;
  unsigned q[8];
#pragma unroll
  for (int i = 0; i < 4; ++i) {
    float4 wv = *(const float4*)(wr + i * 4);
    float4 bv = *(const float4*)(br + i * 4);
    float o0 = (v[i].x - mu) * rstd * wv.x + bv.x;
    float o1 = (v[i].y - mu) * rstd * wv.y + bv.y;
    float o2 = (v[i].z - mu) * rstd * wv.z + bv.z;
    float o3 = (v[i].w - mu) * rstd * wv.w + bv.w;
    q[i*2+0] = pk2(o0, o1);
    q[i*2+1] = pk2(o2, o3);
  }
  uint4* op = (uint4*)(out + (size_t)row * CC + lane * 16);
  op[0] = make_uint4(q[0], q[1], q[2], q[3]);
  op[1] = make_uint4(q[4], q[5], q[6], q[7]);
}

// ---------------- fused reduce + layernorm ----------------
// x[row] += bias + sum_s P[s][row]; out = LN(x[row]) as bf16.
__global__ __launch_bounds__(256) void redln_k(float* __restrict__ x,
    const float* __restrict__ P, const float* __restrict__ bias,
    const float* __restrict__ lw, const float* __restrict__ lb,
    unsigned short* __restrict__ out, int splits)
{
  int row = blockIdx.x * 4 + (threadIdx.x >> 6);
  int lane = threadIdx.x & 63;
  const int c0 = lane * 16;
  float* xw = x + (size_t)row * CC + c0;
  float4 v[4];
#pragma unroll
  for (int i = 0; i < 4; ++i) v[i] = *(const float4*)(xw + i * 4);
  {
    const float4* b4 = (const float4*)(bias + c0);
#pragma unroll
    for (int i = 0; i < 4; ++i) {
      float4 bv = b4[i];
      v[i].x += bv.x; v[i].y += bv.y; v[i].z += bv.z; v[i].w += bv.w;
    }
  }
  for (int sp = 0; sp < splits; ++sp) {
    const float4* p4 = (const float4*)(P + ((size_t)sp * 2048 + row) * CC + c0);
#pragma unroll
    for (int i = 0; i < 4; ++i) {
      float4 pv = p4[i];
      v[i].x += pv.x; v[i].y += pv.y; v[i].z += pv.z; v[i].w += pv.w;
    }
  }
  float s = 0.f, ss = 0.f;
#pragma unroll
  for (int i = 0; i < 4; ++i) {
    *(float4*)(xw + i * 4) = v[i];
    s  += v[i].x + v[i].y + v[i].z + v[i].w;
    ss += v[i].x*v[i].x + v[i].y*v[i].y + v[i].z*v[i].z + v[i].w*v[i].w;
  }
#pragma unroll
  for (int off = 1; off < 64; off <<= 1) {
    s  += __shfl_xor(s, off, 64);
    ss += __shfl_xor(ss, off, 64);
  }
  float mu = s * (1.f / CC);
  float var = ss * (1.f / CC) - mu * mu;
  float rstd = rsqrtf(var + 1e-5f);
  const float* wr = lw + c0;
  const float* br = lb + c0;
  unsigned q[8];
#pragma unroll
  for (int i = 0; i < 4; ++i) {
    float4 wv = *(const float4*)(wr + i * 4);
    float4 bv = *(const float4*)(br + i * 4);
    float o0 = (v[i].x - mu) * rstd * wv.x + bv.x;
    float o1 = (v[i].y - mu) * rstd * wv.y + bv.y;
    float o2 = (v[i].z - mu) * rstd * wv.z + bv.z;
    float o3 = (v[i].w - mu) * rstd * wv.w + bv.w;
    q[i*2+0] = pk2(o0, o1);
    q[i*2+1] = pk2(o2, o3);
  }
  uint4* op = (uint4*)(out + (size_t)row * CC + c0);
  op[0] = make_uint4(q[0], q[1], q[2], q[3]);
  op[1] = make_uint4(q[4], q[5], q[6], q[7]);
}

// ---------------- LN of the last row per batch -> fp32 [2][C] ----------------
__global__ void lnrow_k(const float* __restrict__ x,
    const float* __restrict__ w, const float* __restrict__ b,
    float* __restrict__ outv)
{
  int row = blockIdx.x;   // batch
  int lane = threadIdx.x; // 64
  const float* xr = x + ((size_t)(row * TT + (TT - 1))) * CC + lane * 16;
  float4 v[4];
  float s = 0.f, ss = 0.f;
#pragma unroll
  for (int i = 0; i < 4; ++i) {
    v[i] = *(const float4*)(xr + i * 4);
    s  += v[i].x + v[i].y + v[i].z + v[i].w;
    ss += v[i].x*v[i].x + v[i].y*v[i].y + v[i].z*v[i].z + v[i].w*v[i].w;
  }
#pragma unroll
  for (int off = 1; off < 64; off <<= 1) {
    s  += __shfl_xor(s, off, 64);
    ss += __shfl_xor(ss, off, 64);
  }
  float mu = s * (1.f / CC);
  float var = ss * (1.f / CC) - mu * mu;
  float rstd = rsqrtf(var + 1e-5f);
  float* op = outv + (size_t)row * CC + lane * 16;
  const float* wr = w + lane * 16;
  const float* br = b + lane * 16;
#pragma unroll
  for (int i = 0; i < 4; ++i) {
    float4 wv = *(const float4*)(wr + i * 4);
    float4 bv = *(const float4*)(br + i * 4);
    float4 o;
    o.x = (v[i].x - mu) * rstd * wv.x + bv.x;
    o.y = (v[i].y - mu) * rstd * wv.y + bv.y;
    o.z = (v[i].z - mu) * rstd * wv.z + bv.z;
    o.w = (v[i].w - mu) * rstd * wv.w + bv.w;
    *(float4*)(op + i * 4) = o;
  }
}

// ---------------- weight transpose+convert, batched over layers (z) ----------------
__global__ __launch_bounds__(256) void wconv_k(const float* __restrict__ W,
    unsigned short* __restrict__ Wt, int K, int N)
{
  const size_t lo = (size_t)blockIdx.z * K * N;
  __shared__ float tile[64][65];
  const int k0 = blockIdx.x << 6;
  const int n0 = blockIdx.y << 6;
  const int t = threadIdx.x;
  {
    const int r = t >> 4, c4 = t & 15;
#pragma unroll
    for (int p = 0; p < 4; ++p) {
      int kr = r + (p << 4);
      float4 v = *(const float4*)(W + lo + (size_t)(k0 + kr) * N + n0 + (c4 << 2));
      tile[kr][(c4 << 2) + 0] = v.x;
      tile[kr][(c4 << 2) + 1] = v.y;
      tile[kr][(c4 << 2) + 2] = v.z;
      tile[kr][(c4 << 2) + 3] = v.w;
    }
  }
  __syncthreads();
  {
    const int n = t >> 2, kq = t & 3;
    bf16x8 o0, o1;
#pragma unroll
    for (int e = 0; e < 8; ++e) o0[e] = (short)f2bf(tile[(kq << 4) + e][n]);
#pragma unroll
    for (int e = 0; e < 8; ++e) o1[e] = (short)f2bf(tile[(kq << 4) + 8 + e][n]);
    unsigned short* dst = Wt + lo + (size_t)(n0 + n) * K + k0 + (kq << 4);
    *(bf16x8*)dst = o0;
    *(bf16x8*)(dst + 8) = o1;
  }
}

// ---------------- GEMM modes ----------------
#define MODE_QKV  0
#define MODE_PART 1
#define MODE_FC   2

// Double-buffered m97-style GEMM: prefetch tile t+1 before computing tile t.
template<int MODE>
__global__ __launch_bounds__(256) void gemm_k(
    const unsigned short* __restrict__ A,
    const unsigned short* __restrict__ Wt,
    const float* __restrict__ bias,
    float* __restrict__ pbuf,
    unsigned short* __restrict__ obf,
    unsigned short* __restrict__ q_o,
    unsigned short* __restrict__ k_o,
    unsigned short* __restrict__ v_o,
    int M, int N, int K, int kchunk, int ncol0)
{
  __shared__ alignas(16) unsigned short Asm[2][128 * 64];
  __shared__ alignas(16) unsigned short Bsm[2][128 * 64];
  const int tid  = threadIdx.x;
  const int wave = tid >> 6, lane = tid & 63;
  const int lg = lane >> 4, ll = lane & 15;
  const int nTM = M >> 7, nTN = N >> 7;
  int bid = blockIdx.x;
  const int mt = bid % nTM; bid /= nTM;
  const int nt = bid % nTN;
  const int s  = bid / nTN;
  const int m0 = mt << 7, n0 = nt << 7;
  const int kb = s * kchunk;
  const int nIter = kchunk >> 6;
  const int wm = (wave >> 1) << 6, wn = (wave & 1) << 6;
  f32x4 acc[4][4] = {};

  // staging geometry (uniform per wave-iteration)
  const int grow_ = ((wave << 8) + lane) >> 3;   // base row for c=0 granule group
  // lambda-free stage macro
#define STAGE(BUF, K0)                                                        \
  {                                                                           \
    _Pragma("unroll")                                                         \
    for (int c = 0; c < 4; ++c) {                                             \
      const int seg = (wave << 2) + c;                                        \
      const int g = (seg << 6) + lane;                                        \
      const int row = g >> 3, kq = g & 7;                                     \
      const unsigned short* asrc = A  + (size_t)(m0 + row) * K + (K0) + (kq << 3); \
      const unsigned short* bsrc = Wt + (size_t)(n0 + row) * K + (K0) + (kq << 3); \
      __builtin_amdgcn_global_load_lds(GPTR(asrc), LPTR(&Asm[BUF][seg << 9]), 16, 0, 0); \
      __builtin_amdgcn_global_load_lds(GPTR(bsrc), LPTR(&Bsm[BUF][seg << 9]), 16, 0, 0); \
    }                                                                         \
  }

  STAGE(0, kb);
  int cur = 0;
  for (int t = 0; t < nIter; ++t) {
    __syncthreads();                      // drains vmcnt(0)+lgkmcnt(0) + barrier
    if (t + 1 < nIter) STAGE(cur ^ 1, kb + ((t + 1) << 6));
    const unsigned short* As = &Asm[cur][0];
    const unsigned short* Bs = &Bsm[cur][0];
#pragma unroll
    for (int kk = 0; kk < 2; ++kk) {
      bf16x8 af[4], bfr[4];
#pragma unroll
      for (int i = 0; i < 4; ++i)
        af[i] = *(const bf16x8*)(As + ((wm + i * 16 + ll) << 6) + (kk << 5) + (lg << 3));
#pragma unroll
      for (int j = 0; j < 4; ++j)
        bfr[j] = *(const bf16x8*)(Bs + ((wn + j * 16 + ll) << 6) + (kk << 5) + (lg << 3));
#pragma unroll
      for (int i = 0; i < 4; ++i)
#pragma unroll
        for (int j = 0; j < 4; ++j)
          acc[i][j] = mfma_bf16(af[i], bfr[j], acc[i][j]);
    }
    cur ^= 1;
  }
#undef STAGE

#pragma unroll
  for (int j = 0; j < 4; ++j) {
    int gc = n0 + wn + j * 16 + ll;          // local col
    int gcol = ncol0 + gc;                   // global col (QKV scatter)
    float bv = (MODE == MODE_PART) ? 0.f : bias[gcol];
#pragma unroll
    for (int i = 0; i < 4; ++i) {
      int gr0 = m0 + wm + i * 16 + (lg << 2);
#pragma unroll
      for (int r = 0; r < 4; ++r) {
        int grow = gr0 + r;
        float val = acc[i][j][r] + bv;
        if (MODE == MODE_QKV) {
          int which = gcol >> 10;
          int head = (gcol >> 6) & 15;
          int d = gcol & 63;
          int bb = grow >> 10, t = grow & (TT - 1);
          unsigned short* dst = (which == 0) ? q_o : (which == 1) ? k_o : v_o;
          dst[(((size_t)((bb << 4) + head)) << 16) + ((size_t)t << 6) + d] = f2bf(val);
        } else if (MODE == MODE_FC) {
          val = (val >= 0.f) ? val : 0.01f * val;
          obf[(size_t)grow * N + gc] = f2bf(val);
        } else { // MODE_PART: fp32 partials per split
          pbuf[((size_t)s * M + grow) * N + gc] = val;
        }
      }
    }
  }
}

// ---------------- flash attention (causal), layers 0-2 ----------------
__global__ __launch_bounds__(256) void attn_k(
    const unsigned short* __restrict__ Qb,
    const unsigned short* __restrict__ Kb,
    const unsigned short* __restrict__ Vb,
    unsigned short* __restrict__ ybuf)
{
  __shared__ alignas(16) unsigned short Ksm[64][72];
  __shared__ alignas(16) unsigned short Vtsm[64][64];
  __shared__ alignas(16) unsigned short Psm[4][16][72];
  const int tid = threadIdx.x;
  const int wave = tid >> 6, lane = tid & 63;
  const int lg = lane >> 4, ll = lane & 15;
  const int qt = blockIdx.x & 15, bh = blockIdx.x >> 4;
  const int b = bh >> 4, h = bh & 15;
  const size_t base = (size_t)bh << 16;
  const int q0 = qt << 6;

  const int qrow = q0 + wave * 16 + ll;
  bf16x8 aq0 = *(const bf16x8*)(Qb + base + ((size_t)qrow << 6) + (lg << 3));
  bf16x8 aq1 = *(const bf16x8*)(Qb + base + ((size_t)qrow << 6) + 32 + (lg << 3));

  f32x4 accy[4] = {};
  float m_run[4], l_run[4];
#pragma unroll
  for (int r = 0; r < 4; ++r) { m_run[r] = -1e30f; l_run[r] = 0.f; }

  const int sk_row = tid >> 3, sk_cq = tid & 7;
  const int sv_d = tid & 63, sv_kq = tid >> 6;
  const int qg0 = q0 + wave * 16 + (lg << 2);

  for (int kb = 0; kb <= qt; ++kb) {
    const int kbase = kb << 6;
#pragma unroll
    for (int p = 0; p < 2; ++p) {
      int r = sk_row + (p << 5);
      bf16x8 kv = *(const bf16x8*)(Kb + base + ((size_t)(kbase + r) << 6) + (sk_cq << 3));
      *(bf16x8*)&Ksm[r][sk_cq << 3] = kv;
    }
#pragma unroll
    for (int p = 0; p < 2; ++p) {
      int kq8 = sv_kq + (p << 2);
      bf16x8 wv;
#pragma unroll
      for (int e = 0; e < 8; ++e)
        wv[e] = (short)Vb[base + ((size_t)(kbase + (kq8 << 3) + e) << 6) + sv_d];
      int u = kq8 ^ (sv_d & 7);
      *(bf16x8*)&Vtsm[sv_d][u << 3] = wv;
    }
    __syncthreads();

    float p_[4][4];
    float rmax[4] = {-1e30f, -1e30f, -1e30f, -1e30f};
#pragma unroll
    for (int kk = 0; kk < 4; ++kk) {
      f32x4 z = {};
      bf16x8 bk0 = *(const bf16x8*)&Ksm[kk * 16 + ll][lg << 3];
      bf16x8 bk1 = *(const bf16x8*)&Ksm[kk * 16 + ll][32 + (lg << 3)];
      z = mfma_bf16(aq0, bk0, z);
      z = mfma_bf16(aq1, bk1, z);
      int key = kbase + kk * 16 + ll;
#pragma unroll
      for (int r = 0; r < 4; ++r) {
        float v = z[r] * 0.125f;
        v = (key > qg0 + r) ? -1e30f : v;
        p_[kk][r] = v;
        rmax[r] = fmaxf(rmax[r], v);
      }
    }
#pragma unroll
    for (int off = 1; off < 16; off <<= 1)
#pragma unroll
      for (int r = 0; r < 4; ++r)
        rmax[r] = fmaxf(rmax[r], __shfl_xor(rmax[r], off, 64));

    float alpha[4], rsum[4];
#pragma unroll
    for (int r = 0; r < 4; ++r) {
      float mn = fmaxf(m_run[r], rmax[r]);
      alpha[r] = __expf(m_run[r] - mn);
      m_run[r] = mn;
      rsum[r] = 0.f;
    }
#pragma unroll
    for (int kk = 0; kk < 4; ++kk)
#pragma unroll
      for (int r = 0; r < 4; ++r) {
        float e = __expf(p_[kk][r] - m_run[r]);
        p_[kk][r] = e;
        rsum[r] += e;
      }
#pragma unroll
    for (int off = 1; off < 16; off <<= 1)
#pragma unroll
      for (int r = 0; r < 4; ++r)
        rsum[r] += __shfl_xor(rsum[r], off, 64);
#pragma unroll
    for (int r = 0; r < 4; ++r)
      l_run[r] = l_run[r] * alpha[r] + rsum[r];
#pragma unroll
    for (int df = 0; df < 4; ++df)
#pragma unroll
      for (int r = 0; r < 4; ++r)
        accy[df][r] *= alpha[r];

#pragma unroll
    for (int kk = 0; kk < 4; ++kk)
#pragma unroll
      for (int r = 0; r < 4; ++r)
        Psm[wave][(lg << 2) + r][kk * 16 + ll] = f2bf(p_[kk][r]);
    bf16x8 pa0 = *(const bf16x8*)&Psm[wave][ll][lg << 3];
    bf16x8 pa1 = *(const bf16x8*)&Psm[wave][ll][32 + (lg << 3)];

#pragma unroll
    for (int df = 0; df < 4; ++df) {
      int d = df * 16 + ll;
      int u0 = lg ^ (d & 7);
      int u1 = (4 + lg) ^ (d & 7);
      bf16x8 bv0 = *(const bf16x8*)&Vtsm[d][u0 << 3];
      bf16x8 bv1 = *(const bf16x8*)&Vtsm[d][u1 << 3];
      accy[df] = mfma_bf16(pa0, bv0, accy[df]);
      accy[df] = mfma_bf16(pa1, bv1, accy[df]);
    }
    __syncthreads();
  }

#pragma unroll
  for (int df = 0; df < 4; ++df)
#pragma unroll
    for (int r = 0; r < 4; ++r) {
      int qr = qg0 + r;
      float y = accy[df][r] / l_run[r];
      ybuf[(((size_t)((b << 10) + qr)) << 10) + (h << 6) + df * 16 + ll] = f2bf(y);
    }
}

// ---------------- GEMV stage 1: partials over 128-k slabs ----------------
__global__ __launch_bounds__(256) void gemv_k(const float* __restrict__ W,
    int ldw, const float* __restrict__ xv, int K,
    float* __restrict__ part, int N)
{
  __shared__ float xs[2][128];
  const int tid = threadIdx.x;
  const int n = blockIdx.x * 256 + tid;
  const int ks = blockIdx.y;
  if (tid < 128) xs[0][tid] = xv[ks * 128 + tid];
  else           xs[1][tid - 128] = xv[K + ks * 128 + (tid - 128)];
  __syncthreads();
  float a0 = 0.f, a1 = 0.f;
  const float* wp = W + (size_t)(ks * 128) * ldw + n;
#pragma unroll 4
  for (int k = 0; k < 128; ++k) {
    float w = wp[(size_t)k * ldw];
    a0 += xs[0][k] * w;
    a1 += xs[1][k] * w;
  }
  part[((size_t)ks * 2 + 0) * N + n] = a0;
  part[((size_t)ks * 2 + 1) * N + n] = a1;
}

// ---------------- GEMV merge ----------------
#define MG_PLAIN 0
#define MG_LEAKY 1
#define MG_ADDX  2
template<int MG>
__global__ __launch_bounds__(256) void gmerge_k(const float* __restrict__ part,
    const float* __restrict__ bias, float* __restrict__ outp, int N, int KT)
{
  int n = blockIdx.x * 256 + threadIdx.x;
#pragma unroll
  for (int b = 0; b < 2; ++b) {
    float s = bias[n];
    for (int ks = 0; ks < KT; ++ks)
      s += part[((size_t)ks * 2 + b) * N + n];
    if (MG == MG_PLAIN) outp[(size_t)b * N + n] = s;
    else if (MG == MG_LEAKY) outp[(size_t)b * N + n] = (s >= 0.f) ? s : 0.01f * s;
    else outp[((size_t)(b * TT + TT - 1)) * CC + n] += s;
  }
}

// ---------------- last-query attention, split over key slabs ----------------
__global__ __launch_bounds__(256) void attnlast_k(
    const float* __restrict__ q_last,
    const unsigned short* __restrict__ Kb,
    const unsigned short* __restrict__ Vb,
    float* __restrict__ apart)
{
  __shared__ float qs[64];
  __shared__ float wm[4], wl[4], wacc[4][64];
  const int tid = threadIdx.x;
  const int wave = tid >> 6, lane = tid & 63;
  const int bh = blockIdx.x, ks = blockIdx.y;
  const int b = bh >> 4, h = bh & 15;
  const size_t base = (size_t)bh << 16;
  const int key = ks * 256 + wave * 64 + lane;

  if (tid < 64) qs[tid] = q_last[b * CC + h * 64 + tid];
  __syncthreads();

  float s = 0.f;
  const unsigned short* kp = Kb + base + ((size_t)key << 6);
#pragma unroll
  for (int o = 0; o < 8; ++o) {
    bf16x8 kv = *(const bf16x8*)(kp + (o << 3));
#pragma unroll
    for (int e = 0; e < 8; ++e)
      s += qs[(o << 3) + e] * bf2f((unsigned short)kv[e]);
  }
  s *= 0.125f;
  float m = s;
#pragma unroll
  for (int off = 1; off < 64; off <<= 1)
    m = fmaxf(m, __shfl_xor(m, off, 64));
  float p = __expf(s - m);
  float l = p;
#pragma unroll
  for (int off = 1; off < 64; off <<= 1)
    l += __shfl_xor(l, off, 64);

  float acc = 0.f;
  const unsigned short* vp = Vb + base + ((size_t)(ks * 256 + wave * 64) << 6);
  for (int j = 0; j < 64; ++j) {
    float pj = __shfl(p, j, 64);
    acc += pj * bf2f(vp[((size_t)j << 6) + lane]);
  }
  if (lane == 0) { wm[wave] = m; wl[wave] = l; }
  wacc[wave][lane] = acc;
  __syncthreads();
  if (wave == 0) {
    float m0 = fmaxf(fmaxf(wm[0], wm[1]), fmaxf(wm[2], wm[3]));
    float lt = 0.f, at = 0.f;
#pragma unroll
    for (int sI = 0; sI < 4; ++sI) {
      float f = __expf(wm[sI] - m0);
      lt += wl[sI] * f;
      at += wacc[sI][lane] * f;
    }
    float* op = apart + ((size_t)bh * 4 + ks) * 66;
    if (lane == 0) { op[0] = m0; op[1] = lt; }
    op[2 + lane] = at;
  }
}

__global__ void attnmerge_k(const float* __restrict__ apart,
    float* __restrict__ y_last)
{
  const int bh = blockIdx.x, lane = threadIdx.x;  // 64 threads
  const int b = bh >> 4, h = bh & 15;
  const float* p0 = apart + (size_t)bh * 4 * 66;
  float m0 = fmaxf(fmaxf(p0[0], p0[66]), fmaxf(p0[132], p0[198]));
  float lt = 0.f, at = 0.f;
#pragma unroll
  for (int s = 0; s < 4; ++s) {
    const float* ps = p0 + s * 66;
    float f = __expf(ps[0] - m0);
    lt += ps[1] * f;
    at += ps[2 + lane] * f;
  }
  y_last[b * CC + h * 64 + lane] = at / lt;
}

// ---------------- lm_head ----------------
__global__ __launch_bounds__(256) void head_k(const float* __restrict__ xf,
    const float* __restrict__ wte, float* __restrict__ out)
{
  int v = (blockIdx.x << 2) + (threadIdx.x >> 6);
  if (v >= VOCAB) return;
  int lane = threadIdx.x & 63;
  const float4* wr = (const float4*)(wte + (size_t)v * CC);
  const float4* x0 = (const float4*)xf;
  const float4* x1 = (const float4*)(xf + CC);
  float a0 = 0.f, a1 = 0.f;
#pragma unroll
  for (int i = 0; i < 4; ++i) {
    float4 wv = wr[lane + i * 64];
    float4 p0 = x0[lane + i * 64];
    float4 p1 = x1[lane + i * 64];
    a0 += wv.x * p0.x + wv.y * p0.y + wv.z * p0.z + wv.w * p0.w;
    a1 += wv.x * p1.x + wv.y * p1.y + wv.z * p1.z + wv.w * p1.w;
  }
#pragma unroll
  for (int off = 1; off < 64; off <<= 1) {
    a0 += __shfl_xor(a0, off, 64);
    a1 += __shfl_xor(a1, off, 64);
  }
  if (lane == 0) {
    out[v] = a0;
    out[VOCAB + v] = a1;
  }
}

// ---------------- host orchestration ----------------
extern "C" void kernel_launch(void* const* d_in, const int* in_sizes, int n_in,
                              void* d_out, int out_size, void* d_ws, size_t ws_size,
                              hipStream_t stream)
{
  const int*   idx      = (const int*)d_in[0];
  const float* wte      = (const float*)d_in[1];
  const float* wpe      = (const float*)d_in[2];
  const float* ln1_w    = (const float*)d_in[3];
  const float* ln1_b    = (const float*)d_in[4];
  const float* attn_w   = (const float*)d_in[5];
  const float* attn_b   = (const float*)d_in[6];
  const float* proj_w   = (const float*)d_in[7];
  const float* proj_b   = (const float*)d_in[8];
  const float* ln2_w    = (const float*)d_in[9];
  const float* ln2_b    = (const float*)d_in[10];
  const float* fc_w     = (const float*)d_in[11];
  const float* fc_b     = (const float*)d_in[12];
  const float* fcproj_w = (const float*)d_in[13];
  const float* fcproj_b = (const float*)d_in[14];
  const float* lnf_w    = (const float*)d_in[15];
  const float* lnf_b    = (const float*)d_in[16];
  float* out = (float*)d_out;

  const size_t MB = 1u << 20;
  char* ws = (char*)d_ws;
  float*          x   = (float*)ws;                       // 8 MiB
  unsigned short* h   = (unsigned short*)(ws + 8*MB);     // 4 MiB
  unsigned short* qb  = (unsigned short*)(ws + 12*MB);    // 4 MiB
  unsigned short* kb_ = (unsigned short*)(ws + 16*MB);    // 4 MiB
  unsigned short* vb  = (unsigned short*)(ws + 20*MB);    // 4 MiB
  unsigned short* yb  = (unsigned short*)(ws + 24*MB);    // 4 MiB
  unsigned short* hf  = (unsigned short*)(ws + 28*MB);    // 16 MiB
  char* sm = ws + 44*MB;
  float* xf     = (float*)(sm + 0);
  float* xs1    = (float*)(sm + 16*1024);
  float* xs2    = (float*)(sm + 32*1024);
  float* ylast  = (float*)(sm + 48*1024);
  float* qlast  = (float*)(sm + 64*1024);
  float* hlast  = (float*)(sm + 80*1024);
  float* gpart  = (float*)(sm + 128*1024);
  float* apart  = (float*)(sm + 512*1024);
  unsigned short* wt_attn   = (unsigned short*)(ws + 46*MB);  // 4 x 6 MiB
  unsigned short* wt_proj   = (unsigned short*)(ws + 70*MB);  // 3 x 2 MiB
  unsigned short* wt_fc     = (unsigned short*)(ws + 76*MB);  // 3 x 8 MiB
  unsigned short* wt_fcproj = (unsigned short*)(ws + 100*MB); // 3 x 8 MiB
  float*          Ppart     = (float*)(ws + 124*MB);          // up to 32 MiB

  embed_k<<<NBATCH * TT, 256, 0, stream>>>(idx, wte, wpe, x);

  wconv_k<<<dim3(16, 48, 4), 256, 0, stream>>>(attn_w, wt_attn, 1024, 3072);
  wconv_k<<<dim3(16, 16, 3), 256, 0, stream>>>(proj_w, wt_proj, 1024, 1024);
  wconv_k<<<dim3(16, 64, 3), 256, 0, stream>>>(fc_w, wt_fc, 1024, 4096);
  wconv_k<<<dim3(64, 16, 3), 256, 0, stream>>>(fcproj_w, wt_fcproj, 4096, 1024);

  // ln1 for layer 0 (subsequent LNs are fused into redln_k)
  ln_k<<<512, 256, 0, stream>>>(x, ln1_w, ln1_b, h);

  for (int l = 0; l < 3; ++l) {
    gemm_k<MODE_QKV><<<16 * 24, 256, 0, stream>>>(h,
        wt_attn + (size_t)l * 3072 * 1024, attn_b + (size_t)l * 3 * CC,
        nullptr, nullptr, qb, kb_, vb, 2048, 3072, 1024, 1024, 0);
    attn_k<<<NBATCH * NHEAD * 16, 256, 0, stream>>>(qb, kb_, vb, yb);
    // proj: split-K 4 -> partials -> fused reduce+ln2
    gemm_k<MODE_PART><<<16 * 8 * 4, 256, 0, stream>>>(yb,
        wt_proj + (size_t)l * 1024 * 1024, nullptr,
        Ppart, nullptr, nullptr, nullptr, nullptr, 2048, 1024, 1024, 256, 0);
    redln_k<<<512, 256, 0, stream>>>(x, Ppart, proj_b + l * CC,
        ln2_w + l * CC, ln2_b + l * CC, h, 4);
    gemm_k<MODE_FC><<<16 * 32, 256, 0, stream>>>(h,
        wt_fc + (size_t)l * 1024 * 4096, fc_b + (size_t)l * 4 * CC,
        nullptr, hf, nullptr, nullptr, nullptr, 2048, 4096, 1024, 1024, 0);
    // fcproj: split-K 4 -> partials -> fused reduce+ln1[l+1]
    gemm_k<MODE_PART><<<16 * 8 * 4, 256, 0, stream>>>(hf,
        wt_fcproj + (size_t)l * 4096 * 1024, nullptr,
        Ppart, nullptr, nullptr, nullptr, nullptr, 2048, 1024, 4096, 1024, 0);
    redln_k<<<512, 256, 0, stream>>>(x, Ppart, fcproj_b + l * CC,
        ln1_w + (l + 1) * CC, ln1_b + (l + 1) * CC, h, 4);
  }

  // ---- layer 3: K/V for all positions, everything else last-position only ----
  {
    const int l = 3;
    // h already holds ln1[3](x) from the last redln
    gemm_k<MODE_QKV><<<16 * 16, 256, 0, stream>>>(h,
        wt_attn + (size_t)l * 3072 * 1024 + (size_t)1024 * 1024,
        attn_b + (size_t)l * 3 * CC,
        nullptr, nullptr, qb, kb_, vb, 2048, 2048, 1024, 1024, 1024);
    lnrow_k<<<2, 64, 0, stream>>>(x, ln1_w + l * CC, ln1_b + l * CC, xs1);
    gemv_k<<<dim3(4, 8), 256, 0, stream>>>(attn_w + (size_t)l * CC * 3 * CC,
        3072, xs1, 1024, gpart, 1024);
    gmerge_k<MG_PLAIN><<<4, 256, 0, stream>>>(gpart, attn_b + (size_t)l * 3 * CC,
        qlast, 1024, 8);
    attnlast_k<<<dim3(32, 4), 256, 0, stream>>>(qlast, kb_, vb, apart);
    attnmerge_k<<<32, 64, 0, stream>>>(apart, ylast);
    gemv_k<<<dim3(4, 8), 256, 0, stream>>>(proj_w + (size_t)l * CC * CC,
        1024, ylast, 1024, gpart, 1024);
    gmerge_k<MG_ADDX><<<4, 256, 0, stream>>>(gpart, proj_b + l * CC, x, 1024, 8);
    lnrow_k<<<2, 64, 0, stream>>>(x, ln2_w + l * CC, ln2_b + l * CC, xs2);
    gemv_k<<<dim3(16, 8), 256, 0, stream>>>(fc_w + (size_t)l * CC * 4 * CC,
        4096, xs2, 1024, gpart, 4096);
    gmerge_k<MG_LEAKY><<<16, 256, 0, stream>>>(gpart, fc_b + (size_t)l * 4 * CC,
        hlast, 4096, 8);
    gemv_k<<<dim3(4, 32), 256, 0, stream>>>(fcproj_w + (size_t)l * 4 * CC * CC,
        1024, hlast, 4096, gpart, 1024);
    gmerge_k<MG_ADDX><<<4, 256, 0, stream>>>(gpart, fcproj_b + l * CC, x, 1024, 32);
  }

  lnrow_k<<<2, 64, 0, stream>>>(x, lnf_w, lnf_b, xf);
  head_k<<<(VOCAB + 3) / 4, 256, 0, stream>>>(xf, wte, out);
}